// Round 1
// baseline (1023.270 us; speedup 1.0000x reference)
//
#include <hip/hip_runtime.h>
#include <math.h>

#define BB 2
#define SS 2048
#define EE 1024
#define HH 16
#define DD 64
constexpr int NROWS = BB * SS * HH;          // 65536 rows of D=64
constexpr float SCALE = 0.03125f;            // 1/sqrt(E) = 1/32  (NOT 1/sqrt(D))

// ---------------------------------------------------------------------------
// Kernel 1: QKV projection. x viewed as [B*S*H, D]; q[e] = sum_d x[d]*Wq[e,d].
// Weights (64x64 each) staged in LDS with +1 pad; one wave per row; x value
// broadcast via shfl.
// ---------------------------------------------------------------------------
__global__ __launch_bounds__(256) void qkv_proj(
    const float* __restrict__ x,
    const float* __restrict__ Wq, const float* __restrict__ Wk,
    const float* __restrict__ Wv,
    float* __restrict__ q, float* __restrict__ k, float* __restrict__ v) {
  __shared__ float sW[3][64][65];
  for (int i = threadIdx.x; i < 64 * 64; i += 256) {
    int e = i >> 6, d = i & 63;
    sW[0][e][d] = Wq[i];
    sW[1][e][d] = Wk[i];
    sW[2][e][d] = Wv[i];
  }
  __syncthreads();
  const int lane = threadIdx.x & 63;
  const int wid = blockIdx.x * 4 + (threadIdx.x >> 6);
  const int nw = gridDim.x * 4;
  for (int row = wid; row < NROWS; row += nw) {
    float xv = x[(size_t)row * 64 + lane];
    float aq = 0.f, ak = 0.f, av = 0.f;
#pragma unroll
    for (int d = 0; d < 64; ++d) {
      float xd = __shfl(xv, d, 64);
      aq = fmaf(xd, sW[0][lane][d], aq);
      ak = fmaf(xd, sW[1][lane][d], ak);
      av = fmaf(xd, sW[2][lane][d], av);
    }
    q[(size_t)row * 64 + lane] = aq;
    k[(size_t)row * 64 + lane] = ak;
    v[(size_t)row * 64 + lane] = av;
  }
}

// ---------------------------------------------------------------------------
// Kernel 2: flash-style attention, fp32.
// Block = 256 threads handles 64 query rows of one (b,h).
// K-tile LDS buffer (KPt) is reused for P after the S-GEMM (saves 16 KB,
// keeps static LDS < 64 KB). Online softmax state per q-row (m, l) lives in
// the 16-lane group owning that row.
// Layout of q/k/v: [B,S,H,D] -> row r=(b*S+s)*H+h, contiguous D.
// ---------------------------------------------------------------------------
__global__ __launch_bounds__(256) void attn_kernel(
    const float* __restrict__ q, const float* __restrict__ k,
    const float* __restrict__ v, float* __restrict__ o) {
  __shared__ float Qt[64][65];
  __shared__ float KPt[64][65];  // K tile, later reused as P tile
  __shared__ float Vt[64][65];

  const int qt = blockIdx.x;  // 0..31
  const int h = blockIdx.y;   // 0..15
  const int b = blockIdx.z;   // 0..1
  const int tid = threadIdx.x;
  const int ty = tid >> 4;   // 0..15 -> q-row group
  const int tx = tid & 15;   // 0..15 -> col group
  const int q0 = qt * 64;

  // stage Q tile, pre-scaled
  for (int i = tid; i < 64 * 64; i += 256) {
    int r = i >> 6, c = i & 63;
    Qt[r][c] = q[(((size_t)b * SS + q0 + r) * HH + h) * DD + c] * SCALE;
  }

  float m[4], l[4], acc[4][4];
#pragma unroll
  for (int i = 0; i < 4; ++i) {
    m[i] = -1e30f;
    l[i] = 0.f;
#pragma unroll
    for (int j = 0; j < 4; ++j) acc[i][j] = 0.f;
  }

  for (int kt = 0; kt < SS / 64; ++kt) {
    const int k0 = kt * 64;
    __syncthreads();  // previous iteration done reading KPt/Vt (also covers Qt staging)
    for (int i = tid; i < 64 * 64; i += 256) {
      int r = i >> 6, c = i & 63;
      size_t base = (((size_t)b * SS + k0 + r) * HH + h) * DD + c;
      KPt[r][c] = k[base];
      Vt[r][c] = v[base];
    }
    __syncthreads();

    // S = (Q*scale) K^T : 4x4 microtile per thread
    float s[4][4];
#pragma unroll
    for (int i = 0; i < 4; ++i)
#pragma unroll
      for (int j = 0; j < 4; ++j) s[i][j] = 0.f;
    for (int d = 0; d < 64; ++d) {
      float a_[4], b_[4];
#pragma unroll
      for (int i = 0; i < 4; ++i) a_[i] = Qt[ty * 4 + i][d];
#pragma unroll
      for (int j = 0; j < 4; ++j) b_[j] = KPt[tx * 4 + j][d];
#pragma unroll
      for (int i = 0; i < 4; ++i)
#pragma unroll
        for (int j = 0; j < 4; ++j) s[i][j] = fmaf(a_[i], b_[j], s[i][j]);
    }

    // online softmax per row (rows owned by 16-lane groups: same ty)
    float fscale[4];
#pragma unroll
    for (int i = 0; i < 4; ++i) {
      float rmax = fmaxf(fmaxf(s[i][0], s[i][1]), fmaxf(s[i][2], s[i][3]));
#pragma unroll
      for (int off = 1; off < 16; off <<= 1)
        rmax = fmaxf(rmax, __shfl_xor(rmax, off, 64));
      float mn = fmaxf(m[i], rmax);
      fscale[i] = __expf(m[i] - mn);  // 0 on first tile (m=-1e30)
      m[i] = mn;
      float rsum = 0.f;
#pragma unroll
      for (int j = 0; j < 4; ++j) {
        s[i][j] = __expf(s[i][j] - mn);
        rsum += s[i][j];
      }
#pragma unroll
      for (int off = 1; off < 16; off <<= 1) rsum += __shfl_xor(rsum, off, 64);
      l[i] = l[i] * fscale[i] + rsum;
    }

    __syncthreads();  // all threads done reading KPt (as K)
#pragma unroll
    for (int i = 0; i < 4; ++i)
#pragma unroll
      for (int j = 0; j < 4; ++j) {
        acc[i][j] *= fscale[i];
        KPt[ty * 4 + i][tx * 4 + j] = s[i][j];
      }
    __syncthreads();  // P visible

    // O += P V
    for (int kk = 0; kk < 64; ++kk) {
      float a_[4], b_[4];
#pragma unroll
      for (int i = 0; i < 4; ++i) a_[i] = KPt[ty * 4 + i][kk];
#pragma unroll
      for (int j = 0; j < 4; ++j) b_[j] = Vt[kk][tx * 4 + j];
#pragma unroll
      for (int i = 0; i < 4; ++i)
#pragma unroll
        for (int j = 0; j < 4; ++j) acc[i][j] = fmaf(a_[i], b_[j], acc[i][j]);
    }
  }

  // normalize and write [B,S,H,D]
#pragma unroll
  for (int i = 0; i < 4; ++i) {
    float inv = 1.f / l[i];
#pragma unroll
    for (int j = 0; j < 4; ++j) {
      o[(((size_t)b * SS + q0 + ty * 4 + i) * HH + h) * DD + tx * 4 + j] =
          acc[i][j] * inv;
    }
  }
}

// ---------------------------------------------------------------------------
// Kernel 3: output projection Y[s][eo] = sum_ei A[s][ei]*Wo[eo][ei] + b[eo]
// Standard 64x64 LDS-tiled GEMM (B^T pattern: both tiles read row-major).
// ---------------------------------------------------------------------------
__global__ __launch_bounds__(256) void out_proj(
    const float* __restrict__ a, const float* __restrict__ w,
    const float* __restrict__ bias, float* __restrict__ y) {
  __shared__ float At[64][65];
  __shared__ float Bt[64][65];
  const int tid = threadIdx.x;
  const int ty = tid >> 4, tx = tid & 15;
  const int m0 = blockIdx.x * 64;  // rows over B*S = 4096
  const int n0 = blockIdx.y * 64;  // cols over E = 1024

  float acc[4][4];
#pragma unroll
  for (int i = 0; i < 4; ++i)
#pragma unroll
    for (int j = 0; j < 4; ++j) acc[i][j] = 0.f;

  for (int kt = 0; kt < EE / 64; ++kt) {
    const int k0 = kt * 64;
    __syncthreads();
    for (int i = tid; i < 64 * 64; i += 256) {
      int r = i >> 6, c = i & 63;
      At[r][c] = a[(size_t)(m0 + r) * EE + k0 + c];
      Bt[r][c] = w[(size_t)(n0 + r) * EE + k0 + c];
    }
    __syncthreads();
    for (int kk = 0; kk < 64; ++kk) {
      float a_[4], b_[4];
#pragma unroll
      for (int i = 0; i < 4; ++i) a_[i] = At[ty * 4 + i][kk];
#pragma unroll
      for (int j = 0; j < 4; ++j) b_[j] = Bt[tx * 4 + j][kk];
#pragma unroll
      for (int i = 0; i < 4; ++i)
#pragma unroll
        for (int j = 0; j < 4; ++j) acc[i][j] = fmaf(a_[i], b_[j], acc[i][j]);
    }
  }

#pragma unroll
  for (int i = 0; i < 4; ++i)
#pragma unroll
    for (int j = 0; j < 4; ++j)
      y[(size_t)(m0 + ty * 4 + i) * EE + n0 + tx * 4 + j] =
          acc[i][j] + bias[n0 + tx * 4 + j];
}

// ---------------------------------------------------------------------------
extern "C" void kernel_launch(void* const* d_in, const int* in_sizes, int n_in,
                              void* d_out, int out_size, void* d_ws,
                              size_t ws_size, hipStream_t stream) {
  const float* x = (const float*)d_in[0];
  const float* Wq = (const float*)d_in[1];
  const float* Wk = (const float*)d_in[2];
  const float* Wv = (const float*)d_in[3];
  const float* Wo = (const float*)d_in[4];
  const float* bo = (const float*)d_in[5];
  float* out = (float*)d_out;

  // workspace: q, k, v, att_out -- 4 x 16 MB fp32
  const size_t per = (size_t)NROWS * 64;  // 4,194,304 floats
  float* q = (float*)d_ws;
  float* k = q + per;
  float* v = k + per;
  float* ao = v + per;

  qkv_proj<<<1024, 256, 0, stream>>>(x, Wq, Wk, Wv, q, k, v);
  attn_kernel<<<dim3(32, 16, 2), 256, 0, stream>>>(q, k, v, ao);
  out_proj<<<dim3(64, 16), 256, 0, stream>>>(ao, Wo, bo, out);
}

// Round 2
// 195.439 us; speedup vs baseline: 5.2358x; 5.2358x over previous
//
#include <hip/hip_runtime.h>
#include <math.h>

#define BB 2
#define SS 2048
#define EE 1024
#define HH 16
#define DD 64
constexpr int NROWS = BB * SS * HH;   // 65536 rows of D=64
constexpr float SCALE = 0.03125f;     // 1/sqrt(E) = 1/32

typedef __attribute__((ext_vector_type(8))) short bf16x8;
typedef __attribute__((ext_vector_type(4))) float f32x4;

__device__ inline ushort f2bf(float f) {
  unsigned u = __builtin_bit_cast(unsigned, f);
  u += 0x7fffu + ((u >> 16) & 1u);   // RNE
  return (ushort)(u >> 16);
}

// ---------------------------------------------------------------------------
// Kernel 1: QKV projection -> bf16. q pre-scaled by 1/32 (exact in bf16).
// ---------------------------------------------------------------------------
__global__ __launch_bounds__(256) void qkv_proj(
    const float* __restrict__ x,
    const float* __restrict__ Wq, const float* __restrict__ Wk,
    const float* __restrict__ Wv,
    ushort* __restrict__ qo, ushort* __restrict__ ko, ushort* __restrict__ vo) {
  __shared__ float sW[3][64][65];
  for (int i = threadIdx.x; i < 64 * 64; i += 256) {
    int e = i >> 6, d = i & 63;
    sW[0][e][d] = Wq[i];
    sW[1][e][d] = Wk[i];
    sW[2][e][d] = Wv[i];
  }
  __syncthreads();
  const int lane = threadIdx.x & 63;
  const int wid = blockIdx.x * 4 + (threadIdx.x >> 6);
  const int nw = gridDim.x * 4;
  for (int row = wid; row < NROWS; row += nw) {
    float xv = x[(size_t)row * 64 + lane];
    float aq = 0.f, ak = 0.f, av = 0.f;
#pragma unroll
    for (int d = 0; d < 64; ++d) {
      float xd = __shfl(xv, d, 64);
      aq = fmaf(xd, sW[0][lane][d], aq);
      ak = fmaf(xd, sW[1][lane][d], ak);
      av = fmaf(xd, sW[2][lane][d], av);
    }
    qo[(size_t)row * 64 + lane] = f2bf(aq * SCALE);
    ko[(size_t)row * 64 + lane] = f2bf(ak);
    vo[(size_t)row * 64 + lane] = f2bf(av);
  }
}

// ---------------------------------------------------------------------------
// Kernel 2: transpose V -> vt[B,H,D,S] so attention PV B-frags are contiguous.
// ---------------------------------------------------------------------------
__global__ __launch_bounds__(256) void vtrans(const ushort* __restrict__ v,
                                              ushort* __restrict__ vt) {
  __shared__ __align__(16) ushort T[64][72];
  const int tid = threadIdx.x;
  const int s0 = blockIdx.x * 64, h = blockIdx.y, b = blockIdx.z;
  for (int i = tid; i < 512; i += 256) {
    int r = i >> 3, e0 = (i & 7) * 8;
    *(bf16x8*)&T[r][e0] =
        *(const bf16x8*)&v[(((size_t)b * SS + s0 + r) * HH + h) * DD + e0];
  }
  __syncthreads();
  for (int i = tid; i < 512; i += 256) {
    int d = i >> 3, c0 = (i & 7) * 8;
    bf16x8 tmp;
#pragma unroll
    for (int j = 0; j < 8; ++j) tmp[j] = (short)T[c0 + j][d];
    *(bf16x8*)&vt[(((size_t)b * HH + h) * DD + d) * SS + s0 + c0] = tmp;
  }
}

// ---------------------------------------------------------------------------
// Kernel 3: W_out fp32 -> bf16
// ---------------------------------------------------------------------------
__global__ __launch_bounds__(256) void wcvt(const float* __restrict__ w,
                                            ushort* __restrict__ o) {
  int i = (blockIdx.x * 256 + threadIdx.x) * 8;
  bf16x8 t;
#pragma unroll
  for (int j = 0; j < 8; ++j) t[j] = (short)f2bf(w[i + j]);
  *(bf16x8*)&o[i] = t;
}

// ---------------------------------------------------------------------------
// Kernel 4: MFMA flash attention (no max subtraction: |logit| <= ~2 by
// construction, exp cannot overflow; plain sum-normalize == softmax).
// Block: 256 thr = 4 waves, 64 q-rows (16/wave), 64-key tiles.
// mfma_f32_16x16x32_bf16; A/B frag: lane holds row/col (l&15), 8 contiguous
// k at (l>>4)*8. C/D: col=l&15, row=(l>>4)*4+reg.
// ---------------------------------------------------------------------------
__global__ __launch_bounds__(256) void attn_mfma(
    const ushort* __restrict__ q, const ushort* __restrict__ k,
    const ushort* __restrict__ vt, ushort* __restrict__ o) {
  __shared__ __align__(16) ushort Qs[64 * 72];
  __shared__ __align__(16) ushort Ks[64 * 72];
  __shared__ __align__(16) ushort Vts[64 * 72];
  __shared__ __align__(16) ushort Ps[4 * 16 * 72];
  const int tid = threadIdx.x, w = tid >> 6, l = tid & 63;
  const int g = l >> 4, c = l & 15;
  const int q0 = blockIdx.x * 64, h = blockIdx.y, b = blockIdx.z;

  for (int i = tid; i < 512; i += 256) {
    int r = i >> 3, e0 = (i & 7) * 8;
    *(bf16x8*)&Qs[r * 72 + e0] =
        *(const bf16x8*)&q[(((size_t)b * SS + q0 + r) * HH + h) * DD + e0];
  }
  __syncthreads();
  const bf16x8 aq0 = *(bf16x8*)&Qs[(w * 16 + c) * 72 + g * 8];
  const bf16x8 aq1 = *(bf16x8*)&Qs[(w * 16 + c) * 72 + 32 + g * 8];

  f32x4 accO[4];
  float lacc[4];
#pragma unroll
  for (int t = 0; t < 4; ++t) {
    accO[t] = (f32x4){0.f, 0.f, 0.f, 0.f};
    lacc[t] = 0.f;
  }

  for (int kt = 0; kt < SS / 64; ++kt) {
    const int k0 = kt * 64;
    __syncthreads();  // previous iter done reading Ks/Vts
    for (int i = tid; i < 512; i += 256) {
      int r = i >> 3, e0 = (i & 7) * 8;
      *(bf16x8*)&Ks[r * 72 + e0] =
          *(const bf16x8*)&k[(((size_t)b * SS + k0 + r) * HH + h) * DD + e0];
      *(bf16x8*)&Vts[r * 72 + e0] =
          *(const bf16x8*)&vt[(((size_t)b * HH + h) * DD + r) * SS + k0 + e0];
    }
    __syncthreads();

    // S = Q K^T (16x64 per wave), then p = exp(s)
    float p[4][4];
#pragma unroll
    for (int ct = 0; ct < 4; ++ct) {
      f32x4 s = (f32x4){0.f, 0.f, 0.f, 0.f};
      bf16x8 bk0 = *(bf16x8*)&Ks[(ct * 16 + c) * 72 + g * 8];
      bf16x8 bk1 = *(bf16x8*)&Ks[(ct * 16 + c) * 72 + 32 + g * 8];
      s = __builtin_amdgcn_mfma_f32_16x16x32_bf16(aq0, bk0, s, 0, 0, 0);
      s = __builtin_amdgcn_mfma_f32_16x16x32_bf16(aq1, bk1, s, 0, 0, 0);
#pragma unroll
      for (int r = 0; r < 4; ++r) p[ct][r] = __expf(s[r]);
    }
#pragma unroll
    for (int r = 0; r < 4; ++r)
      lacc[r] += p[0][r] + p[1][r] + p[2][r] + p[3][r];

    // P -> per-wave LDS (C-layout rows g*4+r), then read back as A-frags.
#pragma unroll
    for (int ct = 0; ct < 4; ++ct)
#pragma unroll
      for (int r = 0; r < 4; ++r)
        Ps[w * 1152 + (g * 4 + r) * 72 + ct * 16 + c] = f2bf(p[ct][r]);
    asm volatile("s_waitcnt lgkmcnt(0)" ::: "memory");  // wave-local RAW fence

    bf16x8 ap0 = *(bf16x8*)&Ps[w * 1152 + c * 72 + g * 8];
    bf16x8 ap1 = *(bf16x8*)&Ps[w * 1152 + c * 72 + 32 + g * 8];
#pragma unroll
    for (int ct = 0; ct < 4; ++ct) {
      bf16x8 bv0 = *(bf16x8*)&Vts[(ct * 16 + c) * 72 + g * 8];
      bf16x8 bv1 = *(bf16x8*)&Vts[(ct * 16 + c) * 72 + 32 + g * 8];
      accO[ct] = __builtin_amdgcn_mfma_f32_16x16x32_bf16(ap0, bv0, accO[ct], 0, 0, 0);
      accO[ct] = __builtin_amdgcn_mfma_f32_16x16x32_bf16(ap1, bv1, accO[ct], 0, 0, 0);
    }
  }

  // normalize: row sums live across the 16 c-lanes (xor 1,2,4,8)
#pragma unroll
  for (int r = 0; r < 4; ++r) {
    float t = lacc[r];
    t += __shfl_xor(t, 1, 64);
    t += __shfl_xor(t, 2, 64);
    t += __shfl_xor(t, 4, 64);
    t += __shfl_xor(t, 8, 64);
    lacc[r] = 1.f / t;
  }
#pragma unroll
  for (int ct = 0; ct < 4; ++ct)
#pragma unroll
    for (int r = 0; r < 4; ++r) {
      size_t row = (size_t)b * SS + q0 + w * 16 + g * 4 + r;
      o[row * EE + h * DD + ct * 16 + c] = f2bf(accO[ct][r] * lacc[r]);
    }
}

// ---------------------------------------------------------------------------
// Kernel 5: output projection, bf16 MFMA GEMM. y[m][n] = sum_k a[m][k] w[n][k] + b[n]
// ---------------------------------------------------------------------------
__global__ __launch_bounds__(256) void out_proj_mfma(
    const ushort* __restrict__ a, const ushort* __restrict__ wo,
    const float* __restrict__ bias, float* __restrict__ y) {
  __shared__ __align__(16) ushort As[64 * 72];
  __shared__ __align__(16) ushort Ws[64 * 72];
  const int tid = threadIdx.x, w = tid >> 6, l = tid & 63;
  const int g = l >> 4, c = l & 15;
  const int m0 = blockIdx.x * 64, n0 = blockIdx.y * 64;

  f32x4 acc[4];
#pragma unroll
  for (int t = 0; t < 4; ++t) acc[t] = (f32x4){0.f, 0.f, 0.f, 0.f};

  for (int kt = 0; kt < EE / 64; ++kt) {
    const int k0 = kt * 64;
    __syncthreads();
    for (int i = tid; i < 512; i += 256) {
      int r = i >> 3, e0 = (i & 7) * 8;
      *(bf16x8*)&As[r * 72 + e0] =
          *(const bf16x8*)&a[(size_t)(m0 + r) * EE + k0 + e0];
      *(bf16x8*)&Ws[r * 72 + e0] =
          *(const bf16x8*)&wo[(size_t)(n0 + r) * EE + k0 + e0];
    }
    __syncthreads();
    bf16x8 a0 = *(bf16x8*)&As[(w * 16 + c) * 72 + g * 8];
    bf16x8 a1 = *(bf16x8*)&As[(w * 16 + c) * 72 + 32 + g * 8];
#pragma unroll
    for (int ct = 0; ct < 4; ++ct) {
      bf16x8 b0 = *(bf16x8*)&Ws[(ct * 16 + c) * 72 + g * 8];
      bf16x8 b1 = *(bf16x8*)&Ws[(ct * 16 + c) * 72 + 32 + g * 8];
      acc[ct] = __builtin_amdgcn_mfma_f32_16x16x32_bf16(a0, b0, acc[ct], 0, 0, 0);
      acc[ct] = __builtin_amdgcn_mfma_f32_16x16x32_bf16(a1, b1, acc[ct], 0, 0, 0);
    }
  }
#pragma unroll
  for (int ct = 0; ct < 4; ++ct)
#pragma unroll
    for (int r = 0; r < 4; ++r)
      y[(size_t)(m0 + w * 16 + g * 4 + r) * EE + n0 + ct * 16 + c] =
          acc[ct][r] + bias[n0 + ct * 16 + c];
}

// ---------------------------------------------------------------------------
extern "C" void kernel_launch(void* const* d_in, const int* in_sizes, int n_in,
                              void* d_out, int out_size, void* d_ws,
                              size_t ws_size, hipStream_t stream) {
  const float* x = (const float*)d_in[0];
  const float* Wq = (const float*)d_in[1];
  const float* Wk = (const float*)d_in[2];
  const float* Wv = (const float*)d_in[3];
  const float* Wo = (const float*)d_in[4];
  const float* bo = (const float*)d_in[5];
  float* out = (float*)d_out;

  const size_t per = (size_t)NROWS * 64;  // 4,194,304 bf16 elems = 8 MB
  ushort* qb = (ushort*)d_ws;
  ushort* kb = qb + per;
  ushort* vb = kb + per;
  ushort* vtb = vb + per;
  ushort* aob = vtb + per;
  ushort* wob = aob + per;  // 1M elems = 2 MB  (total 42 MB)

  qkv_proj<<<1024, 256, 0, stream>>>(x, Wq, Wk, Wv, qb, kb, vb);
  vtrans<<<dim3(32, 16, 2), 256, 0, stream>>>(vb, vtb);
  wcvt<<<512, 256, 0, stream>>>(Wo, wob);
  attn_mfma<<<dim3(32, 16, 2), 256, 0, stream>>>(qb, kb, vtb, aob);
  out_proj_mfma<<<dim3(64, 16), 256, 0, stream>>>(aob, wob, bo, out);
}

// Round 3
// 122.438 us; speedup vs baseline: 8.3574x; 1.5962x over previous
//
#include <hip/hip_runtime.h>
#include <math.h>

#define BB 2
#define SS 2048
#define EE 1024
#define HH 16
#define DD 64
constexpr int NROWS = BB * SS * HH;   // 65536 rows of D=64
constexpr float SCALE = 0.03125f;     // 1/sqrt(E) = 1/32

typedef __attribute__((ext_vector_type(8))) short bf16x8;
typedef __attribute__((ext_vector_type(4))) float f32x4;

__device__ inline ushort f2bf(float f) {
  unsigned u = __builtin_bit_cast(unsigned, f);
  u += 0x7fffu + ((u >> 16) & 1u);   // RNE
  return (ushort)(u >> 16);
}

// ---------------------------------------------------------------------------
// Kernel 1: QKV projection as bf16 MFMA GEMM.
// X viewed as [NROWS,64]; q[row][e] = sum_d x[row][d] * Wq[e][d] (then *1/32).
// Block: 256 thr = 4 waves, 128 rows; all 3 weights staged bf16 in LDS.
// ---------------------------------------------------------------------------
__global__ __launch_bounds__(256) void qkv_mfma(
    const float* __restrict__ x,
    const float* __restrict__ Wq, const float* __restrict__ Wk,
    const float* __restrict__ Wv,
    ushort* __restrict__ qo, ushort* __restrict__ ko, ushort* __restrict__ vo) {
  __shared__ __align__(16) ushort Xs[128 * 72];
  __shared__ __align__(16) ushort Ws[3][64 * 72];
  const int tid = threadIdx.x, w = tid >> 6, l = tid & 63;
  const int g = l >> 4, c = l & 15;
  const int m0 = blockIdx.x * 128;

  // stage weights (bf16) -- 12288 elems
  for (int i = tid; i < 3 * 4096; i += 256) {
    int t = i >> 12, j = i & 4095;
    const float* W = (t == 0) ? Wq : ((t == 1) ? Wk : Wv);
    Ws[t][(j >> 6) * 72 + (j & 63)] = f2bf(W[j]);
  }
  // stage X tile (fp32 -> bf16): 8192 elems as float4
  for (int i = tid; i < 2048; i += 256) {
    int r = i >> 4, c4 = (i & 15) * 4;
    float4 xv = *(const float4*)&x[(size_t)(m0 + r) * 64 + c4];
    ushort* dst = &Xs[r * 72 + c4];
    dst[0] = f2bf(xv.x);
    dst[1] = f2bf(xv.y);
    dst[2] = f2bf(xv.z);
    dst[3] = f2bf(xv.w);
  }
  __syncthreads();

  bf16x8 a_[2][2];
#pragma unroll
  for (int rf = 0; rf < 2; ++rf) {
    a_[rf][0] = *(bf16x8*)&Xs[(w * 32 + rf * 16 + c) * 72 + g * 8];
    a_[rf][1] = *(bf16x8*)&Xs[(w * 32 + rf * 16 + c) * 72 + 32 + g * 8];
  }

#pragma unroll
  for (int t = 0; t < 3; ++t) {
    ushort* out = (t == 0) ? qo : ((t == 1) ? ko : vo);
    const float sc = (t == 0) ? SCALE : 1.0f;
#pragma unroll
    for (int ct = 0; ct < 4; ++ct) {
      bf16x8 b0 = *(bf16x8*)&Ws[t][(ct * 16 + c) * 72 + g * 8];
      bf16x8 b1 = *(bf16x8*)&Ws[t][(ct * 16 + c) * 72 + 32 + g * 8];
#pragma unroll
      for (int rf = 0; rf < 2; ++rf) {
        f32x4 acc = (f32x4){0.f, 0.f, 0.f, 0.f};
        acc = __builtin_amdgcn_mfma_f32_16x16x32_bf16(a_[rf][0], b0, acc, 0, 0, 0);
        acc = __builtin_amdgcn_mfma_f32_16x16x32_bf16(a_[rf][1], b1, acc, 0, 0, 0);
#pragma unroll
        for (int r = 0; r < 4; ++r) {
          int row = m0 + w * 32 + rf * 16 + g * 4 + r;
          out[(size_t)row * 64 + ct * 16 + c] = f2bf(acc[r] * sc);
        }
      }
    }
  }
}

// ---------------------------------------------------------------------------
// Kernel 2: transpose V -> vt[B,H,D,S] so attention PV B-frags are contiguous.
// ---------------------------------------------------------------------------
__global__ __launch_bounds__(256) void vtrans(const ushort* __restrict__ v,
                                              ushort* __restrict__ vt) {
  __shared__ __align__(16) ushort T[64][72];
  const int tid = threadIdx.x;
  const int s0 = blockIdx.x * 64, h = blockIdx.y, b = blockIdx.z;
  for (int i = tid; i < 512; i += 256) {
    int r = i >> 3, e0 = (i & 7) * 8;
    *(bf16x8*)&T[r][e0] =
        *(const bf16x8*)&v[(((size_t)b * SS + s0 + r) * HH + h) * DD + e0];
  }
  __syncthreads();
  for (int i = tid; i < 512; i += 256) {
    int d = i >> 3, c0 = (i & 7) * 8;
    bf16x8 tmp;
#pragma unroll
    for (int j = 0; j < 8; ++j) tmp[j] = (short)T[c0 + j][d];
    *(bf16x8*)&vt[(((size_t)b * HH + h) * DD + d) * SS + s0 + c0] = tmp;
  }
}

// ---------------------------------------------------------------------------
// Kernel 3: W_out fp32 -> bf16
// ---------------------------------------------------------------------------
__global__ __launch_bounds__(256) void wcvt(const float* __restrict__ w,
                                            ushort* __restrict__ o) {
  int i = (blockIdx.x * 256 + threadIdx.x) * 8;
  bf16x8 t;
#pragma unroll
  for (int j = 0; j < 8; ++j) t[j] = (short)f2bf(w[i + j]);
  *(bf16x8*)&o[i] = t;
}

// ---------------------------------------------------------------------------
// Kernel 4: MFMA flash attention (no max subtraction: |logit| <= ~2 by
// construction, exp cannot overflow; plain sum-normalize == softmax).
// Block: 256 thr = 4 waves, 64 q-rows (16/wave), 64-key tiles.
// ---------------------------------------------------------------------------
__global__ __launch_bounds__(256) void attn_mfma(
    const ushort* __restrict__ q, const ushort* __restrict__ k,
    const ushort* __restrict__ vt, ushort* __restrict__ o) {
  __shared__ __align__(16) ushort Qs[64 * 72];
  __shared__ __align__(16) ushort Ks[64 * 72];
  __shared__ __align__(16) ushort Vts[64 * 72];
  __shared__ __align__(16) ushort Ps[4 * 16 * 72];
  const int tid = threadIdx.x, w = tid >> 6, l = tid & 63;
  const int g = l >> 4, c = l & 15;
  const int q0 = blockIdx.x * 64, h = blockIdx.y, b = blockIdx.z;

  for (int i = tid; i < 512; i += 256) {
    int r = i >> 3, e0 = (i & 7) * 8;
    *(bf16x8*)&Qs[r * 72 + e0] =
        *(const bf16x8*)&q[(((size_t)b * SS + q0 + r) * HH + h) * DD + e0];
  }
  __syncthreads();
  const bf16x8 aq0 = *(bf16x8*)&Qs[(w * 16 + c) * 72 + g * 8];
  const bf16x8 aq1 = *(bf16x8*)&Qs[(w * 16 + c) * 72 + 32 + g * 8];

  f32x4 accO[4];
  float lacc[4];
#pragma unroll
  for (int t = 0; t < 4; ++t) {
    accO[t] = (f32x4){0.f, 0.f, 0.f, 0.f};
    lacc[t] = 0.f;
  }

  for (int kt = 0; kt < SS / 64; ++kt) {
    const int k0 = kt * 64;
    __syncthreads();  // previous iter done reading Ks/Vts
    for (int i = tid; i < 512; i += 256) {
      int r = i >> 3, e0 = (i & 7) * 8;
      *(bf16x8*)&Ks[r * 72 + e0] =
          *(const bf16x8*)&k[(((size_t)b * SS + k0 + r) * HH + h) * DD + e0];
      *(bf16x8*)&Vts[r * 72 + e0] =
          *(const bf16x8*)&vt[(((size_t)b * HH + h) * DD + r) * SS + k0 + e0];
    }
    __syncthreads();

    // S = Q K^T (16x64 per wave), then p = exp(s)
    float p[4][4];
#pragma unroll
    for (int ct = 0; ct < 4; ++ct) {
      f32x4 s = (f32x4){0.f, 0.f, 0.f, 0.f};
      bf16x8 bk0 = *(bf16x8*)&Ks[(ct * 16 + c) * 72 + g * 8];
      bf16x8 bk1 = *(bf16x8*)&Ks[(ct * 16 + c) * 72 + 32 + g * 8];
      s = __builtin_amdgcn_mfma_f32_16x16x32_bf16(aq0, bk0, s, 0, 0, 0);
      s = __builtin_amdgcn_mfma_f32_16x16x32_bf16(aq1, bk1, s, 0, 0, 0);
#pragma unroll
      for (int r = 0; r < 4; ++r) p[ct][r] = __expf(s[r]);
    }
#pragma unroll
    for (int r = 0; r < 4; ++r)
      lacc[r] += p[0][r] + p[1][r] + p[2][r] + p[3][r];

    // P -> per-wave LDS (C-layout rows g*4+r), then read back as A-frags.
#pragma unroll
    for (int ct = 0; ct < 4; ++ct)
#pragma unroll
      for (int r = 0; r < 4; ++r)
        Ps[w * 1152 + (g * 4 + r) * 72 + ct * 16 + c] = f2bf(p[ct][r]);
    asm volatile("s_waitcnt lgkmcnt(0)" ::: "memory");  // wave-local RAW fence

    bf16x8 ap0 = *(bf16x8*)&Ps[w * 1152 + c * 72 + g * 8];
    bf16x8 ap1 = *(bf16x8*)&Ps[w * 1152 + c * 72 + 32 + g * 8];
#pragma unroll
    for (int ct = 0; ct < 4; ++ct) {
      bf16x8 bv0 = *(bf16x8*)&Vts[(ct * 16 + c) * 72 + g * 8];
      bf16x8 bv1 = *(bf16x8*)&Vts[(ct * 16 + c) * 72 + 32 + g * 8];
      accO[ct] = __builtin_amdgcn_mfma_f32_16x16x32_bf16(ap0, bv0, accO[ct], 0, 0, 0);
      accO[ct] = __builtin_amdgcn_mfma_f32_16x16x32_bf16(ap1, bv1, accO[ct], 0, 0, 0);
    }
  }

  // normalize: row sums live across the 16 c-lanes (xor 1,2,4,8)
#pragma unroll
  for (int r = 0; r < 4; ++r) {
    float t = lacc[r];
    t += __shfl_xor(t, 1, 64);
    t += __shfl_xor(t, 2, 64);
    t += __shfl_xor(t, 4, 64);
    t += __shfl_xor(t, 8, 64);
    lacc[r] = 1.f / t;
  }
#pragma unroll
  for (int ct = 0; ct < 4; ++ct)
#pragma unroll
    for (int r = 0; r < 4; ++r) {
      size_t row = (size_t)b * SS + q0 + w * 16 + g * 4 + r;
      o[row * EE + h * DD + ct * 16 + c] = f2bf(accO[ct][r] * lacc[r]);
    }
}

// ---------------------------------------------------------------------------
// Kernel 5: output projection, bf16 MFMA GEMM. y[m][n] = sum_k a[m][k] w[n][k] + b[n]
// ---------------------------------------------------------------------------
__global__ __launch_bounds__(256) void out_proj_mfma(
    const ushort* __restrict__ a, const ushort* __restrict__ wo,
    const float* __restrict__ bias, float* __restrict__ y) {
  __shared__ __align__(16) ushort As[64 * 72];
  __shared__ __align__(16) ushort Ws[64 * 72];
  const int tid = threadIdx.x, w = tid >> 6, l = tid & 63;
  const int g = l >> 4, c = l & 15;
  const int m0 = blockIdx.x * 64, n0 = blockIdx.y * 64;

  f32x4 acc[4];
#pragma unroll
  for (int t = 0; t < 4; ++t) acc[t] = (f32x4){0.f, 0.f, 0.f, 0.f};

  for (int kt = 0; kt < EE / 64; ++kt) {
    const int k0 = kt * 64;
    __syncthreads();
    for (int i = tid; i < 512; i += 256) {
      int r = i >> 3, e0 = (i & 7) * 8;
      *(bf16x8*)&As[r * 72 + e0] =
          *(const bf16x8*)&a[(size_t)(m0 + r) * EE + k0 + e0];
      *(bf16x8*)&Ws[r * 72 + e0] =
          *(const bf16x8*)&wo[(size_t)(n0 + r) * EE + k0 + e0];
    }
    __syncthreads();
    bf16x8 a0 = *(bf16x8*)&As[(w * 16 + c) * 72 + g * 8];
    bf16x8 a1 = *(bf16x8*)&As[(w * 16 + c) * 72 + 32 + g * 8];
#pragma unroll
    for (int ct = 0; ct < 4; ++ct) {
      bf16x8 b0 = *(bf16x8*)&Ws[(ct * 16 + c) * 72 + g * 8];
      bf16x8 b1 = *(bf16x8*)&Ws[(ct * 16 + c) * 72 + 32 + g * 8];
      acc[ct] = __builtin_amdgcn_mfma_f32_16x16x32_bf16(a0, b0, acc[ct], 0, 0, 0);
      acc[ct] = __builtin_amdgcn_mfma_f32_16x16x32_bf16(a1, b1, acc[ct], 0, 0, 0);
    }
  }
#pragma unroll
  for (int ct = 0; ct < 4; ++ct)
#pragma unroll
    for (int r = 0; r < 4; ++r)
      y[(size_t)(m0 + w * 16 + g * 4 + r) * EE + n0 + ct * 16 + c] =
          acc[ct][r] + bias[n0 + ct * 16 + c];
}

// ---------------------------------------------------------------------------
extern "C" void kernel_launch(void* const* d_in, const int* in_sizes, int n_in,
                              void* d_out, int out_size, void* d_ws,
                              size_t ws_size, hipStream_t stream) {
  const float* x = (const float*)d_in[0];
  const float* Wq = (const float*)d_in[1];
  const float* Wk = (const float*)d_in[2];
  const float* Wv = (const float*)d_in[3];
  const float* Wo = (const float*)d_in[4];
  const float* bo = (const float*)d_in[5];
  float* out = (float*)d_out;

  const size_t per = (size_t)NROWS * 64;  // 4,194,304 bf16 elems = 8 MB
  ushort* qb = (ushort*)d_ws;
  ushort* kb = qb + per;
  ushort* vb = kb + per;
  ushort* vtb = vb + per;
  ushort* aob = vtb + per;
  ushort* wob = aob + per;  // 1M elems = 2 MB  (total 42 MB)

  qkv_mfma<<<512, 256, 0, stream>>>(x, Wq, Wk, Wv, qb, kb, vb);
  vtrans<<<dim3(32, 16, 2), 256, 0, stream>>>(vb, vtb);
  wcvt<<<512, 256, 0, stream>>>(Wo, wob);
  attn_mfma<<<dim3(32, 16, 2), 256, 0, stream>>>(qb, kb, vtb, aob);
  out_proj_mfma<<<dim3(64, 16), 256, 0, stream>>>(aob, wob, bo, out);
}

// Round 4
// 117.418 us; speedup vs baseline: 8.7147x; 1.0428x over previous
//
#include <hip/hip_runtime.h>
#include <math.h>

#define BB 2
#define SS 2048
#define EE 1024
#define HH 16
#define DD 64
constexpr int NROWS = BB * SS * HH;   // 65536 rows of D=64
// q pre-scale: (1/sqrt(E)) * log2(e) so attention can use exp2 directly
constexpr float SCALE_Q = 1.4426950408889634f / 32.0f;

typedef __attribute__((ext_vector_type(8))) short bf16x8;
typedef __attribute__((ext_vector_type(4))) float f32x4;

__device__ inline ushort f2bf(float f) {
  unsigned u = __builtin_bit_cast(unsigned, f);
  u += 0x7fffu + ((u >> 16) & 1u);   // RNE
  return (ushort)(u >> 16);
}

// ---------------------------------------------------------------------------
// Kernel 0: Wq/Wk/Wv fp32 -> bf16 (12288 elems), once.
// ---------------------------------------------------------------------------
__global__ __launch_bounds__(256) void wqkv_cvt(
    const float* __restrict__ Wq, const float* __restrict__ Wk,
    const float* __restrict__ Wv, ushort* __restrict__ o) {
  int i = blockIdx.x * 256 + threadIdx.x;  // grid 48 * 256 = 12288
  int t = i >> 12, j = i & 4095;
  const float* W = (t == 0) ? Wq : ((t == 1) ? Wk : Wv);
  o[i] = f2bf(W[j]);
}

// ---------------------------------------------------------------------------
// Kernel 1: QKV projection as bf16 MFMA GEMM (weights pre-converted).
// q scaled by log2e/32 (folded softmax scale + exp2 conversion).
// ---------------------------------------------------------------------------
__global__ __launch_bounds__(256) void qkv_mfma(
    const float* __restrict__ x, const ushort* __restrict__ wqkv,
    ushort* __restrict__ qo, ushort* __restrict__ ko, ushort* __restrict__ vo) {
  __shared__ __align__(16) ushort Xs[128 * 72];
  __shared__ __align__(16) ushort Ws[3][64 * 72];
  const int tid = threadIdx.x, w = tid >> 6, l = tid & 63;
  const int g = l >> 4, c = l & 15;
  const int m0 = blockIdx.x * 128;

  // stage weights (already bf16): 1536 vector groups
  for (int i = tid; i < 1536; i += 256) {
    int t = i >> 9, j = i & 511;
    int r = j >> 3, e0 = (j & 7) * 8;
    *(bf16x8*)&Ws[t][r * 72 + e0] = *(const bf16x8*)&wqkv[t * 4096 + r * 64 + e0];
  }
  // stage X tile (fp32 -> bf16)
  for (int i = tid; i < 2048; i += 256) {
    int r = i >> 4, c4 = (i & 15) * 4;
    float4 xv = *(const float4*)&x[(size_t)(m0 + r) * 64 + c4];
    ushort* dst = &Xs[r * 72 + c4];
    dst[0] = f2bf(xv.x);
    dst[1] = f2bf(xv.y);
    dst[2] = f2bf(xv.z);
    dst[3] = f2bf(xv.w);
  }
  __syncthreads();

  bf16x8 a_[2][2];
#pragma unroll
  for (int rf = 0; rf < 2; ++rf) {
    a_[rf][0] = *(bf16x8*)&Xs[(w * 32 + rf * 16 + c) * 72 + g * 8];
    a_[rf][1] = *(bf16x8*)&Xs[(w * 32 + rf * 16 + c) * 72 + 32 + g * 8];
  }

#pragma unroll
  for (int t = 0; t < 3; ++t) {
    ushort* out = (t == 0) ? qo : ((t == 1) ? ko : vo);
    const float sc = (t == 0) ? SCALE_Q : 1.0f;
#pragma unroll
    for (int ct = 0; ct < 4; ++ct) {
      bf16x8 b0 = *(bf16x8*)&Ws[t][(ct * 16 + c) * 72 + g * 8];
      bf16x8 b1 = *(bf16x8*)&Ws[t][(ct * 16 + c) * 72 + 32 + g * 8];
#pragma unroll
      for (int rf = 0; rf < 2; ++rf) {
        f32x4 acc = (f32x4){0.f, 0.f, 0.f, 0.f};
        acc = __builtin_amdgcn_mfma_f32_16x16x32_bf16(a_[rf][0], b0, acc, 0, 0, 0);
        acc = __builtin_amdgcn_mfma_f32_16x16x32_bf16(a_[rf][1], b1, acc, 0, 0, 0);
#pragma unroll
        for (int r = 0; r < 4; ++r) {
          int row = m0 + w * 32 + rf * 16 + g * 4 + r;
          out[(size_t)row * 64 + ct * 16 + c] = f2bf(acc[r] * sc);
        }
      }
    }
  }
}

// ---------------------------------------------------------------------------
// Kernel 2: transpose V -> vt[B,H,D,S]
// ---------------------------------------------------------------------------
__global__ __launch_bounds__(256) void vtrans(const ushort* __restrict__ v,
                                              ushort* __restrict__ vt) {
  __shared__ __align__(16) ushort T[64][72];
  const int tid = threadIdx.x;
  const int s0 = blockIdx.x * 64, h = blockIdx.y, b = blockIdx.z;
  for (int i = tid; i < 512; i += 256) {
    int r = i >> 3, e0 = (i & 7) * 8;
    *(bf16x8*)&T[r][e0] =
        *(const bf16x8*)&v[(((size_t)b * SS + s0 + r) * HH + h) * DD + e0];
  }
  __syncthreads();
  for (int i = tid; i < 512; i += 256) {
    int d = i >> 3, c0 = (i & 7) * 8;
    bf16x8 tmp;
#pragma unroll
    for (int j = 0; j < 8; ++j) tmp[j] = (short)T[c0 + j][d];
    *(bf16x8*)&vt[(((size_t)b * HH + h) * DD + d) * SS + s0 + c0] = tmp;
  }
}

// ---------------------------------------------------------------------------
// Kernel 3: W_out fp32 -> bf16
// ---------------------------------------------------------------------------
__global__ __launch_bounds__(256) void wcvt(const float* __restrict__ w,
                                            ushort* __restrict__ o) {
  int i = (blockIdx.x * 256 + threadIdx.x) * 8;
  bf16x8 t;
#pragma unroll
  for (int j = 0; j < 8; ++j) t[j] = (short)f2bf(w[i + j]);
  *(bf16x8*)&o[i] = t;
}

// ---------------------------------------------------------------------------
// Kernel 4: MFMA flash attention.
// QBLK=128 (4 waves x 32 q-rows), KVBLK=64, double-buffered K/V with a single
// barrier per iteration (loads issued pre-compute, LDS writes post-compute).
// p = exp2(s) since Q carries log2e/32. No max subtraction (|s| small).
// Grid: 512 blocks 1-D, XCD-chunk swizzled so each XCD owns 4 (b,h) groups
// (K/V working set 2 MB < 4 MB L2 per XCD).
// ---------------------------------------------------------------------------
__global__ __launch_bounds__(256) void attn_mfma(
    const ushort* __restrict__ q, const ushort* __restrict__ k,
    const ushort* __restrict__ vt, ushort* __restrict__ o) {
  __shared__ __align__(16) ushort Qs[128 * 72];
  __shared__ __align__(16) ushort Ks[2][64 * 72];
  __shared__ __align__(16) ushort Vts[2][64 * 72];
  __shared__ __align__(16) ushort Ps[4 * 32 * 72];
  const int tid = threadIdx.x, w = tid >> 6, l = tid & 63;
  const int g = l >> 4, c = l & 15;
  // XCD swizzle: blockIdx%8 = XCD -> give it a contiguous chunk of 64 works
  const int work = ((blockIdx.x & 7) << 6) | (blockIdx.x >> 3);
  const int qt = work & 15, hb = work >> 4;
  const int h = hb & 15, b = hb >> 4;
  const int q0 = qt * 128;

  const size_t bh_qk = (size_t)b * SS * EE + h * DD;        // + s*EE + d
  const size_t bh_vt = (size_t)b * SS * EE + h * (DD * SS); // + d*SS + s

  for (int i = tid; i < 1024; i += 256) {
    int r = i >> 3, e0 = (i & 7) * 8;
    *(bf16x8*)&Qs[r * 72 + e0] =
        *(const bf16x8*)&q[bh_qk + (size_t)(q0 + r) * EE + e0];
  }
  for (int i = tid; i < 512; i += 256) {
    int r = i >> 3, e0 = (i & 7) * 8;
    *(bf16x8*)&Ks[0][r * 72 + e0] = *(const bf16x8*)&k[bh_qk + (size_t)r * EE + e0];
    *(bf16x8*)&Vts[0][r * 72 + e0] = *(const bf16x8*)&vt[bh_vt + (size_t)r * SS + e0];
  }
  __syncthreads();

  bf16x8 aq[2][2];
#pragma unroll
  for (int rf = 0; rf < 2; ++rf) {
    aq[rf][0] = *(bf16x8*)&Qs[(w * 32 + rf * 16 + c) * 72 + g * 8];
    aq[rf][1] = *(bf16x8*)&Qs[(w * 32 + rf * 16 + c) * 72 + 32 + g * 8];
  }

  f32x4 accO[2][4];
  float lacc[2][4];
#pragma unroll
  for (int rf = 0; rf < 2; ++rf) {
#pragma unroll
    for (int ct = 0; ct < 4; ++ct) accO[rf][ct] = (f32x4){0.f, 0.f, 0.f, 0.f};
#pragma unroll
    for (int r = 0; r < 4; ++r) lacc[rf][r] = 0.f;
  }

  const int sr0 = tid >> 3, se0 = (tid & 7) * 8;  // thread's 2 staging rows: sr0, sr0+32

  for (int t = 0; t < 32; ++t) {
    const int cur = t & 1;
    bf16x8 kr0, kr1, vr0, vr1;
    if (t < 31) {  // issue next tile's loads now; latency hides under MFMAs
      const size_t kb2 = bh_qk + (size_t)((t + 1) * 64) * EE;
      kr0 = *(const bf16x8*)&k[kb2 + (size_t)sr0 * EE + se0];
      kr1 = *(const bf16x8*)&k[kb2 + (size_t)(sr0 + 32) * EE + se0];
      const size_t vb2 = bh_vt + (t + 1) * 64;
      vr0 = *(const bf16x8*)&vt[vb2 + (size_t)sr0 * SS + se0];
      vr1 = *(const bf16x8*)&vt[vb2 + (size_t)(sr0 + 32) * SS + se0];
    }

    // S = Q K^T
    f32x4 s[2][4];
    __builtin_amdgcn_s_setprio(1);
#pragma unroll
    for (int ct = 0; ct < 4; ++ct) {
      bf16x8 bk0 = *(bf16x8*)&Ks[cur][(ct * 16 + c) * 72 + g * 8];
      bf16x8 bk1 = *(bf16x8*)&Ks[cur][(ct * 16 + c) * 72 + 32 + g * 8];
#pragma unroll
      for (int rf = 0; rf < 2; ++rf) {
        f32x4 acc = (f32x4){0.f, 0.f, 0.f, 0.f};
        acc = __builtin_amdgcn_mfma_f32_16x16x32_bf16(aq[rf][0], bk0, acc, 0, 0, 0);
        acc = __builtin_amdgcn_mfma_f32_16x16x32_bf16(aq[rf][1], bk1, acc, 0, 0, 0);
        s[rf][ct] = acc;
      }
    }
    __builtin_amdgcn_s_setprio(0);

    // p = exp2(s), accumulate row sums, store P to wave-local LDS
#pragma unroll
    for (int rf = 0; rf < 2; ++rf)
#pragma unroll
      for (int ct = 0; ct < 4; ++ct)
#pragma unroll
        for (int r = 0; r < 4; ++r) {
          float p = __builtin_amdgcn_exp2f(s[rf][ct][r]);
          lacc[rf][r] += p;
          Ps[w * 2304 + (rf * 16 + g * 4 + r) * 72 + ct * 16 + c] = f2bf(p);
        }
    asm volatile("s_waitcnt lgkmcnt(0)" ::: "memory");  // wave-local RAW fence
    __builtin_amdgcn_sched_barrier(0);

    bf16x8 ap[2][2];
#pragma unroll
    for (int rf = 0; rf < 2; ++rf) {
      ap[rf][0] = *(bf16x8*)&Ps[w * 2304 + (rf * 16 + c) * 72 + g * 8];
      ap[rf][1] = *(bf16x8*)&Ps[w * 2304 + (rf * 16 + c) * 72 + 32 + g * 8];
    }

    // O += P V
    __builtin_amdgcn_s_setprio(1);
#pragma unroll
    for (int ct = 0; ct < 4; ++ct) {
      bf16x8 bv0 = *(bf16x8*)&Vts[cur][(ct * 16 + c) * 72 + g * 8];
      bf16x8 bv1 = *(bf16x8*)&Vts[cur][(ct * 16 + c) * 72 + 32 + g * 8];
#pragma unroll
      for (int rf = 0; rf < 2; ++rf) {
        accO[rf][ct] = __builtin_amdgcn_mfma_f32_16x16x32_bf16(ap[rf][0], bv0, accO[rf][ct], 0, 0, 0);
        accO[rf][ct] = __builtin_amdgcn_mfma_f32_16x16x32_bf16(ap[rf][1], bv1, accO[rf][ct], 0, 0, 0);
      }
    }
    __builtin_amdgcn_s_setprio(0);

    // write next tile into the other buffer (vmcnt wait hidden under MFMAs)
    if (t < 31) {
      const int nxt = cur ^ 1;
      *(bf16x8*)&Ks[nxt][sr0 * 72 + se0] = kr0;
      *(bf16x8*)&Ks[nxt][(sr0 + 32) * 72 + se0] = kr1;
      *(bf16x8*)&Vts[nxt][sr0 * 72 + se0] = vr0;
      *(bf16x8*)&Vts[nxt][(sr0 + 32) * 72 + se0] = vr1;
    }
    __syncthreads();
  }

  // normalize and write
#pragma unroll
  for (int rf = 0; rf < 2; ++rf)
#pragma unroll
    for (int r = 0; r < 4; ++r) {
      float tsum = lacc[rf][r];
      tsum += __shfl_xor(tsum, 1, 64);
      tsum += __shfl_xor(tsum, 2, 64);
      tsum += __shfl_xor(tsum, 4, 64);
      tsum += __shfl_xor(tsum, 8, 64);
      float inv = 1.f / tsum;
#pragma unroll
      for (int ct = 0; ct < 4; ++ct) {
        size_t row = (size_t)b * SS + q0 + w * 32 + rf * 16 + g * 4 + r;
        o[row * EE + h * DD + ct * 16 + c] = f2bf(accO[rf][ct][r] * inv);
      }
    }
}

// ---------------------------------------------------------------------------
// Kernel 5: output projection, bf16 MFMA GEMM.
// ---------------------------------------------------------------------------
__global__ __launch_bounds__(256) void out_proj_mfma(
    const ushort* __restrict__ a, const ushort* __restrict__ wo,
    const float* __restrict__ bias, float* __restrict__ y) {
  __shared__ __align__(16) ushort As[64 * 72];
  __shared__ __align__(16) ushort Ws[64 * 72];
  const int tid = threadIdx.x, w = tid >> 6, l = tid & 63;
  const int g = l >> 4, c = l & 15;
  const int m0 = blockIdx.x * 64, n0 = blockIdx.y * 64;

  f32x4 acc[4];
#pragma unroll
  for (int t = 0; t < 4; ++t) acc[t] = (f32x4){0.f, 0.f, 0.f, 0.f};

  for (int kt = 0; kt < EE / 64; ++kt) {
    const int k0 = kt * 64;
    __syncthreads();
    for (int i = tid; i < 512; i += 256) {
      int r = i >> 3, e0 = (i & 7) * 8;
      *(bf16x8*)&As[r * 72 + e0] =
          *(const bf16x8*)&a[(size_t)(m0 + r) * EE + k0 + e0];
      *(bf16x8*)&Ws[r * 72 + e0] =
          *(const bf16x8*)&wo[(size_t)(n0 + r) * EE + k0 + e0];
    }
    __syncthreads();
    bf16x8 a0 = *(bf16x8*)&As[(w * 16 + c) * 72 + g * 8];
    bf16x8 a1 = *(bf16x8*)&As[(w * 16 + c) * 72 + 32 + g * 8];
#pragma unroll
    for (int ct = 0; ct < 4; ++ct) {
      bf16x8 b0 = *(bf16x8*)&Ws[(ct * 16 + c) * 72 + g * 8];
      bf16x8 b1 = *(bf16x8*)&Ws[(ct * 16 + c) * 72 + 32 + g * 8];
      acc[ct] = __builtin_amdgcn_mfma_f32_16x16x32_bf16(a0, b0, acc[ct], 0, 0, 0);
      acc[ct] = __builtin_amdgcn_mfma_f32_16x16x32_bf16(a1, b1, acc[ct], 0, 0, 0);
    }
  }
#pragma unroll
  for (int ct = 0; ct < 4; ++ct)
#pragma unroll
    for (int r = 0; r < 4; ++r)
      y[(size_t)(m0 + w * 16 + g * 4 + r) * EE + n0 + ct * 16 + c] =
          acc[ct][r] + bias[n0 + ct * 16 + c];
}

// ---------------------------------------------------------------------------
extern "C" void kernel_launch(void* const* d_in, const int* in_sizes, int n_in,
                              void* d_out, int out_size, void* d_ws,
                              size_t ws_size, hipStream_t stream) {
  const float* x = (const float*)d_in[0];
  const float* Wq = (const float*)d_in[1];
  const float* Wk = (const float*)d_in[2];
  const float* Wv = (const float*)d_in[3];
  const float* Wo = (const float*)d_in[4];
  const float* bo = (const float*)d_in[5];
  float* out = (float*)d_out;

  const size_t per = (size_t)NROWS * 64;  // 4,194,304 bf16 elems = 8 MB
  ushort* qb = (ushort*)d_ws;
  ushort* kb = qb + per;
  ushort* vb = kb + per;
  ushort* vtb = vb + per;
  ushort* aob = vtb + per;
  ushort* wob = aob + per;        // 1M elems
  ushort* wqkvb = wob + 1024 * 1024;  // 12288 elems

  wqkv_cvt<<<48, 256, 0, stream>>>(Wq, Wk, Wv, wqkvb);
  wcvt<<<512, 256, 0, stream>>>(Wo, wob);
  qkv_mfma<<<512, 256, 0, stream>>>(x, wqkvb, qb, kb, vb);
  vtrans<<<dim3(32, 16, 2), 256, 0, stream>>>(vb, vtb);
  attn_mfma<<<512, 256, 0, stream>>>(qb, kb, vtb, aob);
  out_proj_mfma<<<dim3(64, 16), 256, 0, stream>>>(aob, wob, bo, out);
}

// Round 5
// 100.762 us; speedup vs baseline: 10.1553x; 1.1653x over previous
//
#include <hip/hip_runtime.h>
#include <math.h>

#define BB 2
#define SS 2048
#define EE 1024
#define HH 16
#define DD 64
constexpr int NROWS = BB * SS * HH;   // 65536 rows of D=64
// q pre-scale: (1/sqrt(E)) * log2(e) so attention can use exp2 directly
constexpr float SCALE_Q = 1.4426950408889634f / 32.0f;

typedef __attribute__((ext_vector_type(8))) short bf16x8;
typedef __attribute__((ext_vector_type(4))) float f32x4;
typedef __attribute__((ext_vector_type(4))) unsigned u32x4;

__device__ inline ushort f2bf(float f) {
  unsigned u = __builtin_bit_cast(unsigned, f);
  u += 0x7fffu + ((u >> 16) & 1u);   // RNE
  return (ushort)(u >> 16);
}

// packed f32x2 -> bf16x2 (RNE), one VALU inst
__device__ inline unsigned cvt_pk(float lo, float hi) {
  unsigned r;
  asm("v_cvt_pk_bf16_f32 %0, %1, %2" : "=v"(r) : "v"(lo), "v"(hi));
  return r;
}

// ---------------------------------------------------------------------------
// Kernel 0: Wq/Wk/Wv fp32 -> bf16 (12288 elems), once.
// ---------------------------------------------------------------------------
__global__ __launch_bounds__(256) void wqkv_cvt(
    const float* __restrict__ Wq, const float* __restrict__ Wk,
    const float* __restrict__ Wv, ushort* __restrict__ o) {
  int i = blockIdx.x * 256 + threadIdx.x;  // grid 48 * 256 = 12288
  int t = i >> 12, j = i & 4095;
  const float* W = (t == 0) ? Wq : ((t == 1) ? Wk : Wv);
  o[i] = f2bf(W[j]);
}

// ---------------------------------------------------------------------------
// Kernel 1: QKV projection as bf16 MFMA GEMM (weights pre-converted).
// q scaled by log2e/32 (folded softmax scale + exp2 conversion).
// ---------------------------------------------------------------------------
__global__ __launch_bounds__(256) void qkv_mfma(
    const float* __restrict__ x, const ushort* __restrict__ wqkv,
    ushort* __restrict__ qo, ushort* __restrict__ ko, ushort* __restrict__ vo) {
  __shared__ __align__(16) ushort Xs[128 * 72];
  __shared__ __align__(16) ushort Ws[3][64 * 72];
  const int tid = threadIdx.x, w = tid >> 6, l = tid & 63;
  const int g = l >> 4, c = l & 15;
  const int m0 = blockIdx.x * 128;

  // stage weights (already bf16): 1536 vector groups
  for (int i = tid; i < 1536; i += 256) {
    int t = i >> 9, j = i & 511;
    int r = j >> 3, e0 = (j & 7) * 8;
    *(bf16x8*)&Ws[t][r * 72 + e0] = *(const bf16x8*)&wqkv[t * 4096 + r * 64 + e0];
  }
  // stage X tile (fp32 -> bf16)
  for (int i = tid; i < 2048; i += 256) {
    int r = i >> 4, c4 = (i & 15) * 4;
    float4 xv = *(const float4*)&x[(size_t)(m0 + r) * 64 + c4];
    ushort* dst = &Xs[r * 72 + c4];
    dst[0] = f2bf(xv.x);
    dst[1] = f2bf(xv.y);
    dst[2] = f2bf(xv.z);
    dst[3] = f2bf(xv.w);
  }
  __syncthreads();

  bf16x8 a_[2][2];
#pragma unroll
  for (int rf = 0; rf < 2; ++rf) {
    a_[rf][0] = *(bf16x8*)&Xs[(w * 32 + rf * 16 + c) * 72 + g * 8];
    a_[rf][1] = *(bf16x8*)&Xs[(w * 32 + rf * 16 + c) * 72 + 32 + g * 8];
  }

#pragma unroll
  for (int t = 0; t < 3; ++t) {
    ushort* out = (t == 0) ? qo : ((t == 1) ? ko : vo);
    const float sc = (t == 0) ? SCALE_Q : 1.0f;
#pragma unroll
    for (int ct = 0; ct < 4; ++ct) {
      bf16x8 b0 = *(bf16x8*)&Ws[t][(ct * 16 + c) * 72 + g * 8];
      bf16x8 b1 = *(bf16x8*)&Ws[t][(ct * 16 + c) * 72 + 32 + g * 8];
#pragma unroll
      for (int rf = 0; rf < 2; ++rf) {
        f32x4 acc = (f32x4){0.f, 0.f, 0.f, 0.f};
        acc = __builtin_amdgcn_mfma_f32_16x16x32_bf16(a_[rf][0], b0, acc, 0, 0, 0);
        acc = __builtin_amdgcn_mfma_f32_16x16x32_bf16(a_[rf][1], b1, acc, 0, 0, 0);
#pragma unroll
        for (int r = 0; r < 4; ++r) {
          int row = m0 + w * 32 + rf * 16 + g * 4 + r;
          out[(size_t)row * 64 + ct * 16 + c] = f2bf(acc[r] * sc);
        }
      }
    }
  }
}

// ---------------------------------------------------------------------------
// Kernel 2: transpose V -> vt[B,H,D,S]
// ---------------------------------------------------------------------------
__global__ __launch_bounds__(256) void vtrans(const ushort* __restrict__ v,
                                              ushort* __restrict__ vt) {
  __shared__ __align__(16) ushort T[64][72];
  const int tid = threadIdx.x;
  const int s0 = blockIdx.x * 64, h = blockIdx.y, b = blockIdx.z;
  for (int i = tid; i < 512; i += 256) {
    int r = i >> 3, e0 = (i & 7) * 8;
    *(bf16x8*)&T[r][e0] =
        *(const bf16x8*)&v[(((size_t)b * SS + s0 + r) * HH + h) * DD + e0];
  }
  __syncthreads();
  for (int i = tid; i < 512; i += 256) {
    int d = i >> 3, c0 = (i & 7) * 8;
    bf16x8 tmp;
#pragma unroll
    for (int j = 0; j < 8; ++j) tmp[j] = (short)T[c0 + j][d];
    *(bf16x8*)&vt[(((size_t)b * HH + h) * DD + d) * SS + s0 + c0] = tmp;
  }
}

// ---------------------------------------------------------------------------
// Kernel 3: W_out fp32 -> bf16
// ---------------------------------------------------------------------------
__global__ __launch_bounds__(256) void wcvt(const float* __restrict__ w,
                                            ushort* __restrict__ o) {
  int i = (blockIdx.x * 256 + threadIdx.x) * 8;
  bf16x8 t;
#pragma unroll
  for (int j = 0; j < 8; ++j) t[j] = (short)f2bf(w[i + j]);
  *(bf16x8*)&o[i] = t;
}

// ---------------------------------------------------------------------------
// Kernel 4: MFMA flash attention, swapped-operand form (S^T = K·Q^T) so the
// whole softmax is lane-local: lane (g,c) owns q-row (c) and keys
// {32kk + 8g + 4o + r}. K is stored in LDS under sigma: key 8g+4o+r ->
// row 16o+4g+r (+32 per half), which makes (a) K A-frag reads natural rows
// kt*16+c, and (b) the S^T C-layout key order EXACTLY the PV B-frag order,
// so P packs to MFMA operands with 16 cvt_pk and no LDS/cross-lane traffic.
// O^T C-layout gives 4 consecutive d per lane -> 8-byte packed stores.
// QBLK=128 (4 waves x 32 q-rows), KVBLK=64, double-buffered, 1 barrier/iter.
// ---------------------------------------------------------------------------
__global__ __launch_bounds__(256) void attn_mfma(
    const ushort* __restrict__ q, const ushort* __restrict__ k,
    const ushort* __restrict__ vt, ushort* __restrict__ o) {
  __shared__ __align__(16) ushort Ks[2][64 * 72];
  __shared__ __align__(16) ushort Vts[2][64 * 72];
  const int tid = threadIdx.x, w = tid >> 6, l = tid & 63;
  const int g = l >> 4, c = l & 15;
  // XCD swizzle: blockIdx%8 = XCD -> contiguous chunk of 64 works
  const int work = ((blockIdx.x & 7) << 6) | (blockIdx.x >> 3);
  const int qt = work & 15, hb = work >> 4;
  const int h = hb & 15, b = hb >> 4;
  const int q0 = qt * 128;

  const size_t bh_qk = (size_t)b * SS * EE + h * DD;        // + s*EE + d
  const size_t bh_vt = (size_t)b * SS * EE + h * (DD * SS); // + d*SS + s

  const int sr0 = tid >> 3;            // 0..31: this thread's key/d row pair
  const int se0 = (tid & 7) * 8;
  // sigma permutation for K LDS rows: key 8g+4o+r -> row 16o+4g+r
  const int krow0 = (((sr0 >> 2) & 1) << 4) | (((sr0 >> 3) & 3) << 2) | (sr0 & 3);

  // prologue: stage tile 0
  {
    bf16x8 kr0 = *(const bf16x8*)&k[bh_qk + (size_t)sr0 * EE + se0];
    bf16x8 kr1 = *(const bf16x8*)&k[bh_qk + (size_t)(sr0 + 32) * EE + se0];
    bf16x8 vr0 = *(const bf16x8*)&vt[bh_vt + (size_t)sr0 * SS + se0];
    bf16x8 vr1 = *(const bf16x8*)&vt[bh_vt + (size_t)(sr0 + 32) * SS + se0];
    *(bf16x8*)&Ks[0][krow0 * 72 + se0] = kr0;
    *(bf16x8*)&Ks[0][(krow0 + 32) * 72 + se0] = kr1;
    *(bf16x8*)&Vts[0][sr0 * 72 + se0] = vr0;
    *(bf16x8*)&Vts[0][(sr0 + 32) * 72 + se0] = vr1;
  }

  // Q B-frags direct from global (lane's q-col = c): 4 x 16B, one-time
  bf16x8 aq[2][2];
#pragma unroll
  for (int qf = 0; qf < 2; ++qf)
#pragma unroll
    for (int dc = 0; dc < 2; ++dc)
      aq[qf][dc] = *(const bf16x8*)&q[bh_qk +
          (size_t)(q0 + w * 32 + qf * 16 + c) * EE + dc * 32 + g * 8];

  f32x4 accO[2][4];
  float lacc[2] = {0.f, 0.f};
#pragma unroll
  for (int qf = 0; qf < 2; ++qf)
#pragma unroll
    for (int ct = 0; ct < 4; ++ct) accO[qf][ct] = (f32x4){0.f, 0.f, 0.f, 0.f};

  __syncthreads();

  for (int t = 0; t < 32; ++t) {
    const int cur = t & 1;
    bf16x8 kr0, kr1, vr0, vr1;
    if (t < 31) {  // issue next tile's loads; latency hides under MFMAs
      const size_t kb2 = bh_qk + (size_t)((t + 1) * 64) * EE;
      kr0 = *(const bf16x8*)&k[kb2 + (size_t)sr0 * EE + se0];
      kr1 = *(const bf16x8*)&k[kb2 + (size_t)(sr0 + 32) * EE + se0];
      const size_t vb2 = bh_vt + (t + 1) * 64;
      vr0 = *(const bf16x8*)&vt[vb2 + (size_t)sr0 * SS + se0];
      vr1 = *(const bf16x8*)&vt[vb2 + (size_t)(sr0 + 32) * SS + se0];
    }

    // S^T = K Q^T: per kt (16 keys), contract d in 2 chunks of 32
    f32x4 s[2][4];  // [qf][kt]
    __builtin_amdgcn_s_setprio(1);
#pragma unroll
    for (int kt = 0; kt < 4; ++kt) {
      bf16x8 ka0 = *(bf16x8*)&Ks[cur][(kt * 16 + c) * 72 + g * 8];
      bf16x8 ka1 = *(bf16x8*)&Ks[cur][(kt * 16 + c) * 72 + 32 + g * 8];
#pragma unroll
      for (int qf = 0; qf < 2; ++qf) {
        f32x4 acc = (f32x4){0.f, 0.f, 0.f, 0.f};
        acc = __builtin_amdgcn_mfma_f32_16x16x32_bf16(ka0, aq[qf][0], acc, 0, 0, 0);
        acc = __builtin_amdgcn_mfma_f32_16x16x32_bf16(ka1, aq[qf][1], acc, 0, 0, 0);
        s[qf][kt] = acc;
      }
    }
    __builtin_amdgcn_s_setprio(0);

    // p = exp2(s) in-register; pack straight into PV B-frag words
    u32x4 pwv[2][2];  // [qf][kk]
#pragma unroll
    for (int qf = 0; qf < 2; ++qf) {
#pragma unroll
      for (int kt = 0; kt < 4; ++kt) {
        float p0 = __builtin_amdgcn_exp2f(s[qf][kt][0]);
        float p1 = __builtin_amdgcn_exp2f(s[qf][kt][1]);
        float p2 = __builtin_amdgcn_exp2f(s[qf][kt][2]);
        float p3 = __builtin_amdgcn_exp2f(s[qf][kt][3]);
        lacc[qf] += (p0 + p1) + (p2 + p3);
        pwv[qf][kt >> 1][(kt & 1) * 2 + 0] = cvt_pk(p0, p1);
        pwv[qf][kt >> 1][(kt & 1) * 2 + 1] = cvt_pk(p2, p3);
      }
    }

    // O^T += V^T P^T
    __builtin_amdgcn_s_setprio(1);
#pragma unroll
    for (int ct = 0; ct < 4; ++ct) {
      bf16x8 va0 = *(bf16x8*)&Vts[cur][(ct * 16 + c) * 72 + g * 8];       // keys kk=0
      bf16x8 va1 = *(bf16x8*)&Vts[cur][(ct * 16 + c) * 72 + 32 + g * 8];  // keys kk=1
#pragma unroll
      for (int qf = 0; qf < 2; ++qf) {
        accO[qf][ct] = __builtin_amdgcn_mfma_f32_16x16x32_bf16(
            va0, __builtin_bit_cast(bf16x8, pwv[qf][0]), accO[qf][ct], 0, 0, 0);
        accO[qf][ct] = __builtin_amdgcn_mfma_f32_16x16x32_bf16(
            va1, __builtin_bit_cast(bf16x8, pwv[qf][1]), accO[qf][ct], 0, 0, 0);
      }
    }
    __builtin_amdgcn_s_setprio(0);

    // write next tile into the other buffer (vmcnt wait hidden under MFMAs)
    if (t < 31) {
      const int nxt = cur ^ 1;
      *(bf16x8*)&Ks[nxt][krow0 * 72 + se0] = kr0;
      *(bf16x8*)&Ks[nxt][(krow0 + 32) * 72 + se0] = kr1;
      *(bf16x8*)&Vts[nxt][sr0 * 72 + se0] = vr0;
      *(bf16x8*)&Vts[nxt][(sr0 + 32) * 72 + se0] = vr1;
    }
    __syncthreads();
  }

  // normalize (row sum spread across the 4 lane-groups) and write packed
#pragma unroll
  for (int qf = 0; qf < 2; ++qf) {
    float tsum = lacc[qf];
    tsum += __shfl_xor(tsum, 16, 64);
    tsum += __shfl_xor(tsum, 32, 64);
    float inv = 1.f / tsum;
    size_t row = (size_t)b * SS + q0 + w * 32 + qf * 16 + c;
#pragma unroll
    for (int ct = 0; ct < 4; ++ct) {
      uint2 pk;
      pk.x = cvt_pk(accO[qf][ct][0] * inv, accO[qf][ct][1] * inv);
      pk.y = cvt_pk(accO[qf][ct][2] * inv, accO[qf][ct][3] * inv);
      *(uint2*)&o[row * EE + h * DD + ct * 16 + g * 4] = pk;
    }
  }
}

// ---------------------------------------------------------------------------
// Kernel 5: output projection, bf16 MFMA GEMM.
// ---------------------------------------------------------------------------
__global__ __launch_bounds__(256) void out_proj_mfma(
    const ushort* __restrict__ a, const ushort* __restrict__ wo,
    const float* __restrict__ bias, float* __restrict__ y) {
  __shared__ __align__(16) ushort As[64 * 72];
  __shared__ __align__(16) ushort Ws[64 * 72];
  const int tid = threadIdx.x, w = tid >> 6, l = tid & 63;
  const int g = l >> 4, c = l & 15;
  const int m0 = blockIdx.x * 64, n0 = blockIdx.y * 64;

  f32x4 acc[4];
#pragma unroll
  for (int t = 0; t < 4; ++t) acc[t] = (f32x4){0.f, 0.f, 0.f, 0.f};

  for (int kt = 0; kt < EE / 64; ++kt) {
    const int k0 = kt * 64;
    __syncthreads();
    for (int i = tid; i < 512; i += 256) {
      int r = i >> 3, e0 = (i & 7) * 8;
      *(bf16x8*)&As[r * 72 + e0] =
          *(const bf16x8*)&a[(size_t)(m0 + r) * EE + k0 + e0];
      *(bf16x8*)&Ws[r * 72 + e0] =
          *(const bf16x8*)&wo[(size_t)(n0 + r) * EE + k0 + e0];
    }
    __syncthreads();
    bf16x8 a0 = *(bf16x8*)&As[(w * 16 + c) * 72 + g * 8];
    bf16x8 a1 = *(bf16x8*)&As[(w * 16 + c) * 72 + 32 + g * 8];
#pragma unroll
    for (int ct = 0; ct < 4; ++ct) {
      bf16x8 b0 = *(bf16x8*)&Ws[(ct * 16 + c) * 72 + g * 8];
      bf16x8 b1 = *(bf16x8*)&Ws[(ct * 16 + c) * 72 + 32 + g * 8];
      acc[ct] = __builtin_amdgcn_mfma_f32_16x16x32_bf16(a0, b0, acc[ct], 0, 0, 0);
      acc[ct] = __builtin_amdgcn_mfma_f32_16x16x32_bf16(a1, b1, acc[ct], 0, 0, 0);
    }
  }
#pragma unroll
  for (int ct = 0; ct < 4; ++ct)
#pragma unroll
    for (int r = 0; r < 4; ++r)
      y[(size_t)(m0 + w * 16 + g * 4 + r) * EE + n0 + ct * 16 + c] =
          acc[ct][r] + bias[n0 + ct * 16 + c];
}

// ---------------------------------------------------------------------------
extern "C" void kernel_launch(void* const* d_in, const int* in_sizes, int n_in,
                              void* d_out, int out_size, void* d_ws,
                              size_t ws_size, hipStream_t stream) {
  const float* x = (const float*)d_in[0];
  const float* Wq = (const float*)d_in[1];
  const float* Wk = (const float*)d_in[2];
  const float* Wv = (const float*)d_in[3];
  const float* Wo = (const float*)d_in[4];
  const float* bo = (const float*)d_in[5];
  float* out = (float*)d_out;

  const size_t per = (size_t)NROWS * 64;  // 4,194,304 bf16 elems = 8 MB
  ushort* qb = (ushort*)d_ws;
  ushort* kb = qb + per;
  ushort* vb = kb + per;
  ushort* vtb = vb + per;
  ushort* aob = vtb + per;
  ushort* wob = aob + per;        // 1M elems
  ushort* wqkvb = wob + 1024 * 1024;  // 12288 elems

  wqkv_cvt<<<48, 256, 0, stream>>>(Wq, Wk, Wv, wqkvb);
  wcvt<<<512, 256, 0, stream>>>(Wo, wob);
  qkv_mfma<<<512, 256, 0, stream>>>(x, wqkvb, qb, kb, vb);
  vtrans<<<dim3(32, 16, 2), 256, 0, stream>>>(vb, vtb);
  attn_mfma<<<512, 256, 0, stream>>>(qb, kb, vtb, aob);
  out_proj_mfma<<<dim3(64, 16), 256, 0, stream>>>(aob, wob, bo, out);
}

// Round 6
// 100.616 us; speedup vs baseline: 10.1701x; 1.0015x over previous
//
#include <hip/hip_runtime.h>
#include <math.h>

#define BB 2
#define SS 2048
#define EE 1024
#define HH 16
#define DD 64
constexpr int NROWS = BB * SS * HH;   // 65536 rows of D=64
// q pre-scale: (1/sqrt(E)) * log2(e) so attention can use exp2 directly
constexpr float SCALE_Q = 1.4426950408889634f / 32.0f;

typedef __attribute__((ext_vector_type(8))) short bf16x8;
typedef __attribute__((ext_vector_type(4))) float f32x4;
typedef __attribute__((ext_vector_type(4))) unsigned u32x4;

__device__ inline ushort f2bf(float f) {
  unsigned u = __builtin_bit_cast(unsigned, f);
  u += 0x7fffu + ((u >> 16) & 1u);   // RNE
  return (ushort)(u >> 16);
}

// packed f32x2 -> bf16x2 (RNE), one VALU inst
__device__ inline unsigned cvt_pk(float lo, float hi) {
  unsigned r;
  asm("v_cvt_pk_bf16_f32 %0, %1, %2" : "=v"(r) : "v"(lo), "v"(hi));
  return r;
}

// ---------------------------------------------------------------------------
// Kernel 0: Wq/Wk/Wv fp32 -> bf16 (12288 elems), once.
// ---------------------------------------------------------------------------
__global__ __launch_bounds__(256) void wqkv_cvt(
    const float* __restrict__ Wq, const float* __restrict__ Wk,
    const float* __restrict__ Wv, ushort* __restrict__ o) {
  int i = blockIdx.x * 256 + threadIdx.x;  // grid 48 * 256 = 12288
  int t = i >> 12, j = i & 4095;
  const float* W = (t == 0) ? Wq : ((t == 1) ? Wk : Wv);
  o[i] = f2bf(W[j]);
}

// ---------------------------------------------------------------------------
// Kernel 1: QKV projection as bf16 MFMA GEMM (weights pre-converted).
// ---------------------------------------------------------------------------
__global__ __launch_bounds__(256) void qkv_mfma(
    const float* __restrict__ x, const ushort* __restrict__ wqkv,
    ushort* __restrict__ qo, ushort* __restrict__ ko, ushort* __restrict__ vo) {
  __shared__ __align__(16) ushort Xs[128 * 72];
  __shared__ __align__(16) ushort Ws[3][64 * 72];
  const int tid = threadIdx.x, w = tid >> 6, l = tid & 63;
  const int g = l >> 4, c = l & 15;
  const int m0 = blockIdx.x * 128;

  for (int i = tid; i < 1536; i += 256) {
    int t = i >> 9, j = i & 511;
    int r = j >> 3, e0 = (j & 7) * 8;
    *(bf16x8*)&Ws[t][r * 72 + e0] = *(const bf16x8*)&wqkv[t * 4096 + r * 64 + e0];
  }
  for (int i = tid; i < 2048; i += 256) {
    int r = i >> 4, c4 = (i & 15) * 4;
    float4 xv = *(const float4*)&x[(size_t)(m0 + r) * 64 + c4];
    ushort* dst = &Xs[r * 72 + c4];
    dst[0] = f2bf(xv.x);
    dst[1] = f2bf(xv.y);
    dst[2] = f2bf(xv.z);
    dst[3] = f2bf(xv.w);
  }
  __syncthreads();

  bf16x8 a_[2][2];
#pragma unroll
  for (int rf = 0; rf < 2; ++rf) {
    a_[rf][0] = *(bf16x8*)&Xs[(w * 32 + rf * 16 + c) * 72 + g * 8];
    a_[rf][1] = *(bf16x8*)&Xs[(w * 32 + rf * 16 + c) * 72 + 32 + g * 8];
  }

#pragma unroll
  for (int t = 0; t < 3; ++t) {
    ushort* out = (t == 0) ? qo : ((t == 1) ? ko : vo);
    const float sc = (t == 0) ? SCALE_Q : 1.0f;
#pragma unroll
    for (int ct = 0; ct < 4; ++ct) {
      bf16x8 b0 = *(bf16x8*)&Ws[t][(ct * 16 + c) * 72 + g * 8];
      bf16x8 b1 = *(bf16x8*)&Ws[t][(ct * 16 + c) * 72 + 32 + g * 8];
#pragma unroll
      for (int rf = 0; rf < 2; ++rf) {
        f32x4 acc = (f32x4){0.f, 0.f, 0.f, 0.f};
        acc = __builtin_amdgcn_mfma_f32_16x16x32_bf16(a_[rf][0], b0, acc, 0, 0, 0);
        acc = __builtin_amdgcn_mfma_f32_16x16x32_bf16(a_[rf][1], b1, acc, 0, 0, 0);
#pragma unroll
        for (int r = 0; r < 4; ++r) {
          int row = m0 + w * 32 + rf * 16 + g * 4 + r;
          out[(size_t)row * 64 + ct * 16 + c] = f2bf(acc[r] * sc);
        }
      }
    }
  }
}

// ---------------------------------------------------------------------------
// Kernel 2: transpose V -> vt[B,H,D,S]
// ---------------------------------------------------------------------------
__global__ __launch_bounds__(256) void vtrans(const ushort* __restrict__ v,
                                              ushort* __restrict__ vt) {
  __shared__ __align__(16) ushort T[64][72];
  const int tid = threadIdx.x;
  const int s0 = blockIdx.x * 64, h = blockIdx.y, b = blockIdx.z;
  for (int i = tid; i < 512; i += 256) {
    int r = i >> 3, e0 = (i & 7) * 8;
    *(bf16x8*)&T[r][e0] =
        *(const bf16x8*)&v[(((size_t)b * SS + s0 + r) * HH + h) * DD + e0];
  }
  __syncthreads();
  for (int i = tid; i < 512; i += 256) {
    int d = i >> 3, c0 = (i & 7) * 8;
    bf16x8 tmp;
#pragma unroll
    for (int j = 0; j < 8; ++j) tmp[j] = (short)T[c0 + j][d];
    *(bf16x8*)&vt[(((size_t)b * HH + h) * DD + d) * SS + s0 + c0] = tmp;
  }
}

// ---------------------------------------------------------------------------
// Kernel 3: W_out fp32 -> bf16
// ---------------------------------------------------------------------------
__global__ __launch_bounds__(256) void wcvt(const float* __restrict__ w,
                                            ushort* __restrict__ o) {
  int i = (blockIdx.x * 256 + threadIdx.x) * 8;
  bf16x8 t;
#pragma unroll
  for (int j = 0; j < 8; ++j) t[j] = (short)f2bf(w[i + j]);
  *(bf16x8*)&o[i] = t;
}

// ---------------------------------------------------------------------------
// Kernel 4: MFMA flash attention, swapped-operand (S^T = K·Q^T), softmax
// fully lane-local (see r5 notes). QBLK=64 (4 waves x 16 q-rows) -> grid
// 1024 = 4 blocks/CU for occupancy; KVBLK=64, double-buffered, 1 barrier/it.
// ---------------------------------------------------------------------------
__global__ __launch_bounds__(256) void attn_mfma(
    const ushort* __restrict__ q, const ushort* __restrict__ k,
    const ushort* __restrict__ vt, ushort* __restrict__ o) {
  __shared__ __align__(16) ushort Ks[2][64 * 72];
  __shared__ __align__(16) ushort Vts[2][64 * 72];
  const int tid = threadIdx.x, w = tid >> 6, l = tid & 63;
  const int g = l >> 4, c = l & 15;
  // XCD swizzle: blockIdx%8 = XCD -> contiguous chunk of 128 works
  const int work = ((blockIdx.x & 7) << 7) | (blockIdx.x >> 3);
  const int qt = work & 31, hb = work >> 5;
  const int h = hb & 15, b = hb >> 4;
  const int q0 = qt * 64;

  const size_t bh_qk = (size_t)b * SS * EE + h * DD;        // + s*EE + d
  const size_t bh_vt = (size_t)b * SS * EE + h * (DD * SS); // + d*SS + s

  const int sr0 = tid >> 3;            // 0..31: this thread's key/d row pair
  const int se0 = (tid & 7) * 8;
  // sigma permutation for K LDS rows: key 8g+4o+r -> row 16o+4g+r
  const int krow0 = (((sr0 >> 2) & 1) << 4) | (((sr0 >> 3) & 3) << 2) | (sr0 & 3);

  // prologue: stage tile 0
  {
    bf16x8 kr0 = *(const bf16x8*)&k[bh_qk + (size_t)sr0 * EE + se0];
    bf16x8 kr1 = *(const bf16x8*)&k[bh_qk + (size_t)(sr0 + 32) * EE + se0];
    bf16x8 vr0 = *(const bf16x8*)&vt[bh_vt + (size_t)sr0 * SS + se0];
    bf16x8 vr1 = *(const bf16x8*)&vt[bh_vt + (size_t)(sr0 + 32) * SS + se0];
    *(bf16x8*)&Ks[0][krow0 * 72 + se0] = kr0;
    *(bf16x8*)&Ks[0][(krow0 + 32) * 72 + se0] = kr1;
    *(bf16x8*)&Vts[0][sr0 * 72 + se0] = vr0;
    *(bf16x8*)&Vts[0][(sr0 + 32) * 72 + se0] = vr1;
  }

  // Q B-frags direct from global (lane's q-row = c): 2 x 16B, one-time
  bf16x8 aq[2];
#pragma unroll
  for (int dc = 0; dc < 2; ++dc)
    aq[dc] = *(const bf16x8*)&q[bh_qk +
        (size_t)(q0 + w * 16 + c) * EE + dc * 32 + g * 8];

  f32x4 accO[4];
  float lacc = 0.f;
#pragma unroll
  for (int ct = 0; ct < 4; ++ct) accO[ct] = (f32x4){0.f, 0.f, 0.f, 0.f};

  __syncthreads();

  for (int t = 0; t < 32; ++t) {
    const int cur = t & 1;
    bf16x8 kr0, kr1, vr0, vr1;
    if (t < 31) {  // issue next tile's loads; latency hides under MFMAs
      const size_t kb2 = bh_qk + (size_t)((t + 1) * 64) * EE;
      kr0 = *(const bf16x8*)&k[kb2 + (size_t)sr0 * EE + se0];
      kr1 = *(const bf16x8*)&k[kb2 + (size_t)(sr0 + 32) * EE + se0];
      const size_t vb2 = bh_vt + (t + 1) * 64;
      vr0 = *(const bf16x8*)&vt[vb2 + (size_t)sr0 * SS + se0];
      vr1 = *(const bf16x8*)&vt[vb2 + (size_t)(sr0 + 32) * SS + se0];
    }

    // S^T = K Q^T: per kt (16 keys), contract d in 2 chunks of 32
    f32x4 s[4];
    __builtin_amdgcn_s_setprio(1);
#pragma unroll
    for (int kt = 0; kt < 4; ++kt) {
      bf16x8 ka0 = *(bf16x8*)&Ks[cur][(kt * 16 + c) * 72 + g * 8];
      bf16x8 ka1 = *(bf16x8*)&Ks[cur][(kt * 16 + c) * 72 + 32 + g * 8];
      f32x4 acc = (f32x4){0.f, 0.f, 0.f, 0.f};
      acc = __builtin_amdgcn_mfma_f32_16x16x32_bf16(ka0, aq[0], acc, 0, 0, 0);
      acc = __builtin_amdgcn_mfma_f32_16x16x32_bf16(ka1, aq[1], acc, 0, 0, 0);
      s[kt] = acc;
    }
    __builtin_amdgcn_s_setprio(0);

    // p = exp2(s) in-register; pack straight into PV B-frag words
    u32x4 pwv[2];
#pragma unroll
    for (int kt = 0; kt < 4; ++kt) {
      float p0 = __builtin_amdgcn_exp2f(s[kt][0]);
      float p1 = __builtin_amdgcn_exp2f(s[kt][1]);
      float p2 = __builtin_amdgcn_exp2f(s[kt][2]);
      float p3 = __builtin_amdgcn_exp2f(s[kt][3]);
      lacc += (p0 + p1) + (p2 + p3);
      pwv[kt >> 1][(kt & 1) * 2 + 0] = cvt_pk(p0, p1);
      pwv[kt >> 1][(kt & 1) * 2 + 1] = cvt_pk(p2, p3);
    }

    // O^T += V^T P^T
    __builtin_amdgcn_s_setprio(1);
#pragma unroll
    for (int ct = 0; ct < 4; ++ct) {
      bf16x8 va0 = *(bf16x8*)&Vts[cur][(ct * 16 + c) * 72 + g * 8];
      bf16x8 va1 = *(bf16x8*)&Vts[cur][(ct * 16 + c) * 72 + 32 + g * 8];
      accO[ct] = __builtin_amdgcn_mfma_f32_16x16x32_bf16(
          va0, __builtin_bit_cast(bf16x8, pwv[0]), accO[ct], 0, 0, 0);
      accO[ct] = __builtin_amdgcn_mfma_f32_16x16x32_bf16(
          va1, __builtin_bit_cast(bf16x8, pwv[1]), accO[ct], 0, 0, 0);
    }
    __builtin_amdgcn_s_setprio(0);

    // write next tile into the other buffer (vmcnt wait hidden under MFMAs)
    if (t < 31) {
      const int nxt = cur ^ 1;
      *(bf16x8*)&Ks[nxt][krow0 * 72 + se0] = kr0;
      *(bf16x8*)&Ks[nxt][(krow0 + 32) * 72 + se0] = kr1;
      *(bf16x8*)&Vts[nxt][sr0 * 72 + se0] = vr0;
      *(bf16x8*)&Vts[nxt][(sr0 + 32) * 72 + se0] = vr1;
    }
    __syncthreads();
  }

  // normalize (row sum spread across the 4 lane-groups) and write packed
  {
    float tsum = lacc;
    tsum += __shfl_xor(tsum, 16, 64);
    tsum += __shfl_xor(tsum, 32, 64);
    float inv = 1.f / tsum;
    size_t row = (size_t)b * SS + q0 + w * 16 + c;
#pragma unroll
    for (int ct = 0; ct < 4; ++ct) {
      uint2 pk;
      pk.x = cvt_pk(accO[ct][0] * inv, accO[ct][1] * inv);
      pk.y = cvt_pk(accO[ct][2] * inv, accO[ct][3] * inv);
      *(uint2*)&o[row * EE + h * DD + ct * 16 + g * 4] = pk;
    }
  }
}

// ---------------------------------------------------------------------------
// Kernel 5: output projection, bf16 MFMA GEMM, 128x64 tile, reg-staged
// double-buffer, 1 barrier per K-step (mirrors attn staging).
// y[m][n] = sum_k a[m][k] wo[n][k] + bias[n]
// ---------------------------------------------------------------------------
__global__ __launch_bounds__(256) void out_proj_mfma(
    const ushort* __restrict__ a, const ushort* __restrict__ wo,
    const float* __restrict__ bias, float* __restrict__ y) {
  __shared__ __align__(16) ushort As[2][128 * 72];
  __shared__ __align__(16) ushort Ws[2][64 * 72];
  const int tid = threadIdx.x, w = tid >> 6, l = tid & 63;
  const int g = l >> 4, c = l & 15;
  const int m0 = blockIdx.x * 128, n0 = blockIdx.y * 64;

  // staging coords: A 1024 vecs (4/thread), B 512 vecs (2/thread)
  const int ar = tid >> 1, ae = (tid & 1) * 8;          // A: rows 0..127, 2 vec-cols {0,8}? no:
  // A row-major [128][64]: vec v = r*8 + e8 (e8 in 0..7). thread covers v=tid*4..tid*4+3?
  // simpler: v in {tid + j*256}: r = v >> 3, e0 = (v & 7) * 8
  const int sr = tid >> 3, se = (tid & 7) * 8;

  f32x4 acc[2][4];
#pragma unroll
  for (int mf = 0; mf < 2; ++mf)
#pragma unroll
    for (int ct = 0; ct < 4; ++ct) acc[mf][ct] = (f32x4){0.f, 0.f, 0.f, 0.f};

  // prologue: stage k0=0 into buf 0
  {
#pragma unroll
    for (int j = 0; j < 4; ++j) {
      int r = sr + j * 32;
      *(bf16x8*)&As[0][r * 72 + se] = *(const bf16x8*)&a[(size_t)(m0 + r) * EE + se];
    }
#pragma unroll
    for (int j = 0; j < 2; ++j) {
      int r = sr + j * 32;
      *(bf16x8*)&Ws[0][r * 72 + se] = *(const bf16x8*)&wo[(size_t)(n0 + r) * EE + se];
    }
  }
  __syncthreads();

  for (int t = 0; t < 16; ++t) {
    const int cur = t & 1;
    bf16x8 Arg[4], Brg[2];
    if (t < 15) {
      const int k0 = (t + 1) * 64;
#pragma unroll
      for (int j = 0; j < 4; ++j) {
        int r = sr + j * 32;
        Arg[j] = *(const bf16x8*)&a[(size_t)(m0 + r) * EE + k0 + se];
      }
#pragma unroll
      for (int j = 0; j < 2; ++j) {
        int r = sr + j * 32;
        Brg[j] = *(const bf16x8*)&wo[(size_t)(n0 + r) * EE + k0 + se];
      }
    }

    bf16x8 af[2][2];
#pragma unroll
    for (int mf = 0; mf < 2; ++mf) {
      af[mf][0] = *(bf16x8*)&As[cur][(w * 32 + mf * 16 + c) * 72 + g * 8];
      af[mf][1] = *(bf16x8*)&As[cur][(w * 32 + mf * 16 + c) * 72 + 32 + g * 8];
    }
    __builtin_amdgcn_s_setprio(1);
#pragma unroll
    for (int ct = 0; ct < 4; ++ct) {
      bf16x8 b0 = *(bf16x8*)&Ws[cur][(ct * 16 + c) * 72 + g * 8];
      bf16x8 b1 = *(bf16x8*)&Ws[cur][(ct * 16 + c) * 72 + 32 + g * 8];
#pragma unroll
      for (int mf = 0; mf < 2; ++mf) {
        acc[mf][ct] = __builtin_amdgcn_mfma_f32_16x16x32_bf16(af[mf][0], b0, acc[mf][ct], 0, 0, 0);
        acc[mf][ct] = __builtin_amdgcn_mfma_f32_16x16x32_bf16(af[mf][1], b1, acc[mf][ct], 0, 0, 0);
      }
    }
    __builtin_amdgcn_s_setprio(0);

    if (t < 15) {
      const int nxt = cur ^ 1;
#pragma unroll
      for (int j = 0; j < 4; ++j) {
        int r = sr + j * 32;
        *(bf16x8*)&As[nxt][r * 72 + se] = Arg[j];
      }
#pragma unroll
      for (int j = 0; j < 2; ++j) {
        int r = sr + j * 32;
        *(bf16x8*)&Ws[nxt][r * 72 + se] = Brg[j];
      }
    }
    __syncthreads();
  }

#pragma unroll
  for (int ct = 0; ct < 4; ++ct) {
    float bv = bias[n0 + ct * 16 + c];
#pragma unroll
    for (int mf = 0; mf < 2; ++mf)
#pragma unroll
      for (int r = 0; r < 4; ++r)
        y[(size_t)(m0 + w * 32 + mf * 16 + g * 4 + r) * EE + n0 + ct * 16 + c] =
            acc[mf][ct][r] + bv;
  }
}

// ---------------------------------------------------------------------------
extern "C" void kernel_launch(void* const* d_in, const int* in_sizes, int n_in,
                              void* d_out, int out_size, void* d_ws,
                              size_t ws_size, hipStream_t stream) {
  const float* x = (const float*)d_in[0];
  const float* Wq = (const float*)d_in[1];
  const float* Wk = (const float*)d_in[2];
  const float* Wv = (const float*)d_in[3];
  const float* Wo = (const float*)d_in[4];
  const float* bo = (const float*)d_in[5];
  float* out = (float*)d_out;

  const size_t per = (size_t)NROWS * 64;  // 4,194,304 bf16 elems = 8 MB
  ushort* qb = (ushort*)d_ws;
  ushort* kb = qb + per;
  ushort* vb = kb + per;
  ushort* vtb = vb + per;
  ushort* aob = vtb + per;
  ushort* wob = aob + per;        // 1M elems
  ushort* wqkvb = wob + 1024 * 1024;  // 12288 elems

  wqkv_cvt<<<48, 256, 0, stream>>>(Wq, Wk, Wv, wqkvb);
  wcvt<<<512, 256, 0, stream>>>(Wo, wob);
  qkv_mfma<<<512, 256, 0, stream>>>(x, wqkvb, qb, kb, vb);
  vtrans<<<dim3(32, 16, 2), 256, 0, stream>>>(vb, vtb);
  attn_mfma<<<1024, 256, 0, stream>>>(qb, kb, vtb, aob);
  out_proj_mfma<<<dim3(32, 16), 256, 0, stream>>>(aob, wob, bo, out);
}

// Round 7
// 89.749 us; speedup vs baseline: 11.4014x; 1.1211x over previous
//
#include <hip/hip_runtime.h>
#include <math.h>

#define BB 2
#define SS 2048
#define EE 1024
#define HH 16
#define DD 64
constexpr int NROWS = BB * SS * HH;   // 65536 rows of D=64
// q pre-scale: (1/sqrt(E)) * log2(e) so attention can use exp2 directly
constexpr float SCALE_Q = 1.4426950408889634f / 32.0f;

typedef __attribute__((ext_vector_type(8))) short bf16x8;
typedef __attribute__((ext_vector_type(4))) float f32x4;
typedef __attribute__((ext_vector_type(16))) float f32x16;
typedef __attribute__((ext_vector_type(4))) unsigned u32x4;

__device__ inline ushort f2bf(float f) {
  unsigned u = __builtin_bit_cast(unsigned, f);
  u += 0x7fffu + ((u >> 16) & 1u);   // RNE
  return (ushort)(u >> 16);
}

// packed f32x2 -> bf16x2 (RNE), one VALU inst
__device__ inline unsigned cvt_pk(float lo, float hi) {
  unsigned r;
  asm("v_cvt_pk_bf16_f32 %0, %1, %2" : "=v"(r) : "v"(lo), "v"(hi));
  return r;
}

// ---------------------------------------------------------------------------
// Kernel 0: Wq/Wk/Wv fp32 -> bf16 (12288 elems), once.
// ---------------------------------------------------------------------------
__global__ __launch_bounds__(256) void wqkv_cvt(
    const float* __restrict__ Wq, const float* __restrict__ Wk,
    const float* __restrict__ Wv, ushort* __restrict__ o) {
  int i = blockIdx.x * 256 + threadIdx.x;  // grid 48 * 256 = 12288
  int t = i >> 12, j = i & 4095;
  const float* W = (t == 0) ? Wq : ((t == 1) ? Wk : Wv);
  o[i] = f2bf(W[j]);
}

// ---------------------------------------------------------------------------
// Kernel 1: QKV projection, h-major blocks (fixed b,h; 128 s-rows).
// q,k written [B,S,H,D]; V written TRANSPOSED [B,H,D,S] directly (the C
// layout gives 4 consecutive s per lane -> packed 8B stores), so the
// separate vtrans kernel is gone.
// ---------------------------------------------------------------------------
__global__ __launch_bounds__(256) void qkv_mfma(
    const float* __restrict__ x, const ushort* __restrict__ wqkv,
    ushort* __restrict__ qo, ushort* __restrict__ ko, ushort* __restrict__ vto) {
  __shared__ __align__(16) ushort Xs[128 * 72];
  __shared__ __align__(16) ushort Ws[3][64 * 72];
  const int tid = threadIdx.x, w = tid >> 6, l = tid & 63;
  const int g = l >> 4, c = l & 15;
  const int s0 = blockIdx.x * 128, h = blockIdx.y, b = blockIdx.z;

  for (int i = tid; i < 1536; i += 256) {
    int t = i >> 9, j = i & 511;
    int r = j >> 3, e0 = (j & 7) * 8;
    *(bf16x8*)&Ws[t][r * 72 + e0] = *(const bf16x8*)&wqkv[t * 4096 + r * 64 + e0];
  }
  for (int i = tid; i < 2048; i += 256) {
    int r = i >> 4, c4 = (i & 15) * 4;
    float4 xv = *(const float4*)&x[(((size_t)b * SS + s0 + r) * HH + h) * DD + c4];
    uint2 pk;
    pk.x = cvt_pk(xv.x, xv.y);
    pk.y = cvt_pk(xv.z, xv.w);
    *(uint2*)&Xs[r * 72 + c4] = pk;
  }
  __syncthreads();

  bf16x8 a_[2][2];
#pragma unroll
  for (int rf = 0; rf < 2; ++rf) {
    a_[rf][0] = *(bf16x8*)&Xs[(w * 32 + rf * 16 + c) * 72 + g * 8];
    a_[rf][1] = *(bf16x8*)&Xs[(w * 32 + rf * 16 + c) * 72 + 32 + g * 8];
  }

  // q and k: row-major [B,S,H,D]
#pragma unroll
  for (int t = 0; t < 2; ++t) {
    ushort* out = (t == 0) ? qo : ko;
    const float sc = (t == 0) ? SCALE_Q : 1.0f;
#pragma unroll
    for (int ct = 0; ct < 4; ++ct) {
      bf16x8 b0 = *(bf16x8*)&Ws[t][(ct * 16 + c) * 72 + g * 8];
      bf16x8 b1 = *(bf16x8*)&Ws[t][(ct * 16 + c) * 72 + 32 + g * 8];
#pragma unroll
      for (int rf = 0; rf < 2; ++rf) {
        f32x4 acc = (f32x4){0.f, 0.f, 0.f, 0.f};
        acc = __builtin_amdgcn_mfma_f32_16x16x32_bf16(a_[rf][0], b0, acc, 0, 0, 0);
        acc = __builtin_amdgcn_mfma_f32_16x16x32_bf16(a_[rf][1], b1, acc, 0, 0, 0);
#pragma unroll
        for (int r = 0; r < 4; ++r) {
          int srow = w * 32 + rf * 16 + g * 4 + r;
          out[(((size_t)b * SS + s0 + srow) * HH + h) * DD + ct * 16 + c] =
              f2bf(acc[r] * sc);
        }
      }
    }
  }
  // v: transposed [B,H,D,S], packed 8B stores
#pragma unroll
  for (int ct = 0; ct < 4; ++ct) {
    bf16x8 b0 = *(bf16x8*)&Ws[2][(ct * 16 + c) * 72 + g * 8];
    bf16x8 b1 = *(bf16x8*)&Ws[2][(ct * 16 + c) * 72 + 32 + g * 8];
#pragma unroll
    for (int rf = 0; rf < 2; ++rf) {
      f32x4 acc = (f32x4){0.f, 0.f, 0.f, 0.f};
      acc = __builtin_amdgcn_mfma_f32_16x16x32_bf16(a_[rf][0], b0, acc, 0, 0, 0);
      acc = __builtin_amdgcn_mfma_f32_16x16x32_bf16(a_[rf][1], b1, acc, 0, 0, 0);
      uint2 pk;
      pk.x = cvt_pk(acc[0], acc[1]);
      pk.y = cvt_pk(acc[2], acc[3]);
      int d = ct * 16 + c;
      int srow = w * 32 + rf * 16 + g * 4;
      *(uint2*)&vto[(((size_t)b * HH + h) * DD + d) * SS + s0 + srow] = pk;
    }
  }
}

// ---------------------------------------------------------------------------
// Kernel 3: W_out fp32 -> bf16
// ---------------------------------------------------------------------------
__global__ __launch_bounds__(256) void wcvt(const float* __restrict__ w,
                                            ushort* __restrict__ o) {
  int i = (blockIdx.x * 256 + threadIdx.x) * 8;
  bf16x8 t;
#pragma unroll
  for (int j = 0; j < 8; ++j) t[j] = (short)f2bf(w[i + j]);
  *(bf16x8*)&o[i] = t;
}

// ---------------------------------------------------------------------------
// Kernel 4: MFMA flash attention on 32x32x16 (2x FLOP per LDS byte vs 16x16).
// Swapped S^T = K·Q^T; K rows stored under sigma = swap bits 2,3 of the key
// index so the S^T C-regs in natural order ARE the PV B-frag key order:
//   C label p=(r&3)+8(r>>2)+4h  ->  actual key = (r&3)+4((r>>2)&1)+8h+16(r>>3)
//   => regs r=0..7 give keys 8h+0..7 of 16-key block 0, r=8..15 block 1.
// P -> PV operands = 16 cvt_pk, zero LDS. O^T C-layout -> packed 8B stores.
// QBLK=128 (4 waves x 32 q), KVBLK=64, double-buffered, 1 barrier/iter.
// ---------------------------------------------------------------------------
__global__ __launch_bounds__(256) void attn_mfma(
    const ushort* __restrict__ q, const ushort* __restrict__ k,
    const ushort* __restrict__ vt, ushort* __restrict__ o) {
  __shared__ __align__(16) ushort Ks[2][64 * 72];
  __shared__ __align__(16) ushort Vts[2][64 * 72];
  const int tid = threadIdx.x, w = tid >> 6, l = tid & 63;
  const int lq = l & 31, h2 = l >> 5;  // q-col, lane half
  // XCD swizzle: blockIdx%8 = XCD -> contiguous chunk of 64 works
  const int work = ((blockIdx.x & 7) << 6) | (blockIdx.x >> 3);
  const int qt = work & 15, hb = work >> 4;
  const int h = hb & 15, b = hb >> 4;
  const int q0 = qt * 128;

  const size_t bh_qk = (size_t)b * SS * EE + h * DD;        // + s*EE + d
  const size_t bh_vt = (size_t)b * SS * EE + h * (DD * SS); // + d*SS + s

  const int sr0 = tid >> 3;            // 0..31
  const int se0 = (tid & 7) * 8;
  // sigma: swap bits 2 and 3 of the key index (bits 0,1,4 kept)
  const int krow0 = (sr0 & 19) | ((sr0 & 4) << 1) | ((sr0 & 8) >> 1);

  // prologue: stage tile 0
  {
    bf16x8 kr0 = *(const bf16x8*)&k[bh_qk + (size_t)sr0 * EE + se0];
    bf16x8 kr1 = *(const bf16x8*)&k[bh_qk + (size_t)(sr0 + 32) * EE + se0];
    bf16x8 vr0 = *(const bf16x8*)&vt[bh_vt + (size_t)sr0 * SS + se0];
    bf16x8 vr1 = *(const bf16x8*)&vt[bh_vt + (size_t)(sr0 + 32) * SS + se0];
    *(bf16x8*)&Ks[0][krow0 * 72 + se0] = kr0;
    *(bf16x8*)&Ks[0][(krow0 + 32) * 72 + se0] = kr1;
    *(bf16x8*)&Vts[0][sr0 * 72 + se0] = vr0;
    *(bf16x8*)&Vts[0][(sr0 + 32) * 72 + se0] = vr1;
  }

  // Q B-frags direct from global: lane's q-row = q0 + w*32 + lq,
  // depth block db: elems db*16 + h2*8 .. +8
  bf16x8 aq[4];
#pragma unroll
  for (int db = 0; db < 4; ++db)
    aq[db] = *(const bf16x8*)&q[bh_qk +
        (size_t)(q0 + w * 32 + lq) * EE + db * 16 + h2 * 8];

  f32x16 accO[2];
  float lacc = 0.f;
#pragma unroll
  for (int ct = 0; ct < 2; ++ct)
#pragma unroll
    for (int r = 0; r < 16; ++r) accO[ct][r] = 0.f;

  __syncthreads();

  for (int t = 0; t < 32; ++t) {
    const int cur = t & 1;
    bf16x8 kr0, kr1, vr0, vr1;
    if (t < 31) {  // issue next tile's loads; latency hides under MFMAs
      const size_t kb2 = bh_qk + (size_t)((t + 1) * 64) * EE;
      kr0 = *(const bf16x8*)&k[kb2 + (size_t)sr0 * EE + se0];
      kr1 = *(const bf16x8*)&k[kb2 + (size_t)(sr0 + 32) * EE + se0];
      const size_t vb2 = bh_vt + (t + 1) * 64;
      vr0 = *(const bf16x8*)&vt[vb2 + (size_t)sr0 * SS + se0];
      vr1 = *(const bf16x8*)&vt[vb2 + (size_t)(sr0 + 32) * SS + se0];
    }

    // S^T = K Q^T: 2 key-blocks x 4 depth-blocks
    f32x16 s[2];
    __builtin_amdgcn_s_setprio(1);
#pragma unroll
    for (int kb = 0; kb < 2; ++kb) {
      f32x16 acc;
#pragma unroll
      for (int r = 0; r < 16; ++r) acc[r] = 0.f;
#pragma unroll
      for (int db = 0; db < 4; ++db) {
        bf16x8 ka = *(bf16x8*)&Ks[cur][(kb * 32 + lq) * 72 + db * 16 + h2 * 8];
        acc = __builtin_amdgcn_mfma_f32_32x32x16_bf16(ka, aq[db], acc, 0, 0, 0);
      }
      s[kb] = acc;
    }
    __builtin_amdgcn_s_setprio(0);

    // p = exp2(s); regs t16*8 + j are exactly PV B-frag key order
    u32x4 pwv[2][2];  // [kb][t16]
#pragma unroll
    for (int kb = 0; kb < 2; ++kb)
#pragma unroll
      for (int t16 = 0; t16 < 2; ++t16)
#pragma unroll
        for (int j2 = 0; j2 < 4; ++j2) {
          float pa = __builtin_amdgcn_exp2f(s[kb][t16 * 8 + j2 * 2]);
          float pb = __builtin_amdgcn_exp2f(s[kb][t16 * 8 + j2 * 2 + 1]);
          lacc += pa + pb;
          pwv[kb][t16][j2] = cvt_pk(pa, pb);
        }

    // O^T += V^T P^T: 2 d-blocks x (2 kb x 2 t16) key16-blocks
    __builtin_amdgcn_s_setprio(1);
#pragma unroll
    for (int ct = 0; ct < 2; ++ct) {
#pragma unroll
      for (int kb = 0; kb < 2; ++kb)
#pragma unroll
        for (int t16 = 0; t16 < 2; ++t16) {
          bf16x8 va = *(bf16x8*)&Vts[cur][(ct * 32 + lq) * 72 +
                                          kb * 32 + t16 * 16 + h2 * 8];
          accO[ct] = __builtin_amdgcn_mfma_f32_32x32x16_bf16(
              va, __builtin_bit_cast(bf16x8, pwv[kb][t16]), accO[ct], 0, 0, 0);
        }
    }
    __builtin_amdgcn_s_setprio(0);

    // write next tile into the other buffer (vmcnt hidden under MFMAs)
    if (t < 31) {
      const int nxt = cur ^ 1;
      *(bf16x8*)&Ks[nxt][krow0 * 72 + se0] = kr0;
      *(bf16x8*)&Ks[nxt][(krow0 + 32) * 72 + se0] = kr1;
      *(bf16x8*)&Vts[nxt][sr0 * 72 + se0] = vr0;
      *(bf16x8*)&Vts[nxt][(sr0 + 32) * 72 + se0] = vr1;
    }
    __syncthreads();
  }

  // normalize: halves of the wave hold complementary key sums for same q
  {
    float tsum = lacc + __shfl_xor(lacc, 32, 64);
    float inv = 1.f / tsum;
    size_t row = (size_t)b * SS + q0 + w * 32 + lq;
#pragma unroll
    for (int ct = 0; ct < 2; ++ct)
#pragma unroll
      for (int rq = 0; rq < 4; ++rq) {
        uint2 pk;
        pk.x = cvt_pk(accO[ct][rq * 4 + 0] * inv, accO[ct][rq * 4 + 1] * inv);
        pk.y = cvt_pk(accO[ct][rq * 4 + 2] * inv, accO[ct][rq * 4 + 3] * inv);
        *(uint2*)&o[row * EE + h * DD + ct * 32 + rq * 8 + h2 * 4] = pk;
      }
  }
}

// ---------------------------------------------------------------------------
// Kernel 5: output projection, bf16 MFMA GEMM, 128x64 tile, reg-staged
// double-buffer, 1 barrier per K-step.
// ---------------------------------------------------------------------------
__global__ __launch_bounds__(256) void out_proj_mfma(
    const ushort* __restrict__ a, const ushort* __restrict__ wo,
    const float* __restrict__ bias, float* __restrict__ y) {
  __shared__ __align__(16) ushort As[2][128 * 72];
  __shared__ __align__(16) ushort Ws[2][64 * 72];
  const int tid = threadIdx.x, w = tid >> 6, l = tid & 63;
  const int g = l >> 4, c = l & 15;
  const int m0 = blockIdx.x * 128, n0 = blockIdx.y * 64;
  const int sr = tid >> 3, se = (tid & 7) * 8;

  f32x4 acc[2][4];
#pragma unroll
  for (int mf = 0; mf < 2; ++mf)
#pragma unroll
    for (int ct = 0; ct < 4; ++ct) acc[mf][ct] = (f32x4){0.f, 0.f, 0.f, 0.f};

  {
#pragma unroll
    for (int j = 0; j < 4; ++j) {
      int r = sr + j * 32;
      *(bf16x8*)&As[0][r * 72 + se] = *(const bf16x8*)&a[(size_t)(m0 + r) * EE + se];
    }
#pragma unroll
    for (int j = 0; j < 2; ++j) {
      int r = sr + j * 32;
      *(bf16x8*)&Ws[0][r * 72 + se] = *(const bf16x8*)&wo[(size_t)(n0 + r) * EE + se];
    }
  }
  __syncthreads();

  for (int t = 0; t < 16; ++t) {
    const int cur = t & 1;
    bf16x8 Arg[4], Brg[2];
    if (t < 15) {
      const int k0 = (t + 1) * 64;
#pragma unroll
      for (int j = 0; j < 4; ++j) {
        int r = sr + j * 32;
        Arg[j] = *(const bf16x8*)&a[(size_t)(m0 + r) * EE + k0 + se];
      }
#pragma unroll
      for (int j = 0; j < 2; ++j) {
        int r = sr + j * 32;
        Brg[j] = *(const bf16x8*)&wo[(size_t)(n0 + r) * EE + k0 + se];
      }
    }

    bf16x8 af[2][2];
#pragma unroll
    for (int mf = 0; mf < 2; ++mf) {
      af[mf][0] = *(bf16x8*)&As[cur][(w * 32 + mf * 16 + c) * 72 + g * 8];
      af[mf][1] = *(bf16x8*)&As[cur][(w * 32 + mf * 16 + c) * 72 + 32 + g * 8];
    }
    __builtin_amdgcn_s_setprio(1);
#pragma unroll
    for (int ct = 0; ct < 4; ++ct) {
      bf16x8 b0 = *(bf16x8*)&Ws[cur][(ct * 16 + c) * 72 + g * 8];
      bf16x8 b1 = *(bf16x8*)&Ws[cur][(ct * 16 + c) * 72 + 32 + g * 8];
#pragma unroll
      for (int mf = 0; mf < 2; ++mf) {
        acc[mf][ct] = __builtin_amdgcn_mfma_f32_16x16x32_bf16(af[mf][0], b0, acc[mf][ct], 0, 0, 0);
        acc[mf][ct] = __builtin_amdgcn_mfma_f32_16x16x32_bf16(af[mf][1], b1, acc[mf][ct], 0, 0, 0);
      }
    }
    __builtin_amdgcn_s_setprio(0);

    if (t < 15) {
      const int nxt = cur ^ 1;
#pragma unroll
      for (int j = 0; j < 4; ++j) {
        int r = sr + j * 32;
        *(bf16x8*)&As[nxt][r * 72 + se] = Arg[j];
      }
#pragma unroll
      for (int j = 0; j < 2; ++j) {
        int r = sr + j * 32;
        *(bf16x8*)&Ws[nxt][r * 72 + se] = Brg[j];
      }
    }
    __syncthreads();
  }

#pragma unroll
  for (int ct = 0; ct < 4; ++ct) {
    float bv = bias[n0 + ct * 16 + c];
#pragma unroll
    for (int mf = 0; mf < 2; ++mf)
#pragma unroll
      for (int r = 0; r < 4; ++r)
        y[(size_t)(m0 + w * 32 + mf * 16 + g * 4 + r) * EE + n0 + ct * 16 + c] =
            acc[mf][ct][r] + bv;
  }
}

// ---------------------------------------------------------------------------
extern "C" void kernel_launch(void* const* d_in, const int* in_sizes, int n_in,
                              void* d_out, int out_size, void* d_ws,
                              size_t ws_size, hipStream_t stream) {
  const float* x = (const float*)d_in[0];
  const float* Wq = (const float*)d_in[1];
  const float* Wk = (const float*)d_in[2];
  const float* Wv = (const float*)d_in[3];
  const float* Wo = (const float*)d_in[4];
  const float* bo = (const float*)d_in[5];
  float* out = (float*)d_out;

  const size_t per = (size_t)NROWS * 64;  // 4,194,304 bf16 elems = 8 MB
  ushort* qb = (ushort*)d_ws;
  ushort* kb = qb + per;
  ushort* vtb = kb + per;
  ushort* aob = vtb + per;
  ushort* wob = aob + per;            // 1M elems
  ushort* wqkvb = wob + 1024 * 1024;  // 12288 elems

  wqkv_cvt<<<48, 256, 0, stream>>>(Wq, Wk, Wv, wqkvb);
  wcvt<<<512, 256, 0, stream>>>(Wo, wob);
  qkv_mfma<<<dim3(16, 16, 2), 256, 0, stream>>>(x, wqkvb, qb, kb, vtb);
  attn_mfma<<<512, 256, 0, stream>>>(qb, kb, vtb, aob);
  out_proj_mfma<<<dim3(32, 16), 256, 0, stream>>>(aob, wob, bo, out);
}